// Round 5
// baseline (345.539 us; speedup 1.0000x reference)
//
#include <hip/hip_runtime.h>
#include <hip/hip_bf16.h>
#include <math.h>

typedef __attribute__((ext_vector_type(8))) short short8;
typedef __attribute__((ext_vector_type(4))) short short4v;
typedef __attribute__((ext_vector_type(4))) float f32x4;

#define DEV __device__ __forceinline__

DEV short f2bf(float f) {
  unsigned u = __builtin_bit_cast(unsigned, f);
  unsigned r = (u + 0x7FFFu + ((u >> 16) & 1u)) >> 16;
  return (short)r;
}

DEV short f2h(float f) {
  _Float16 h = (_Float16)f;
  return __builtin_bit_cast(short, h);
}

DEV float h2f(short s) {
  return (float)__builtin_bit_cast(_Float16, s);
}

DEV unsigned cvt_pk_bf16(float lo, float hi) {
  unsigned r;
  asm("v_cvt_pk_bf16_f32 %0, %1, %2" : "=v"(r) : "v"(lo), "v"(hi));
  return r;
}

DEV void gload_lds16(const void* g, void* l) {
  __builtin_amdgcn_global_load_lds((const __attribute__((address_space(1))) void*)g,
                                   (__attribute__((address_space(3))) void*)l, 16, 0, 0);
}

// C[M x N] (f32, row-major) = A[M x K] (bf16, row-major) * BT[N x K]^T (bf16 row-major N x K)
// 2-phase double-buffered: prefetch K-step k+1 issued BEFORE compute of k; one barrier/step.
__global__ __launch_bounds__(256) void gemm_bf16(const short* __restrict__ A,
                                                 const short* __restrict__ BT,
                                                 float* __restrict__ C,
                                                 int M, int N, int K) {
  __shared__ __attribute__((aligned(16))) short As[2][128 * 32];
  __shared__ __attribute__((aligned(16))) short Bs[2][128 * 32];
  const int tid = threadIdx.x;
  const int w = tid >> 6, l = tid & 63;
  const int g = l >> 4, lr = l & 15;
  const int m0 = blockIdx.y * 128, n0 = blockIdx.x * 128;
  const int wr = w >> 1, wc = w & 1;
  const int q0 = w * 2, q1 = w * 2 + 1;
  const int e0 = q0 * 512 + l * 8, e1 = q1 * 512 + l * 8;
  const int ra = e0 >> 5, ka = e0 & 31;
  const int rb_ = e1 >> 5, kb_ = e1 & 31;
  f32x4 acc[4][4] = {};

  auto stage = [&](int buf, int k0) {
    gload_lds16(A + (size_t)(m0 + ra) * K + k0 + ka, As[buf] + q0 * 512);
    gload_lds16(BT + (size_t)(n0 + ra) * K + k0 + ka, Bs[buf] + q0 * 512);
    gload_lds16(A + (size_t)(m0 + rb_) * K + k0 + kb_, As[buf] + q1 * 512);
    gload_lds16(BT + (size_t)(n0 + rb_) * K + k0 + kb_, Bs[buf] + q1 * 512);
  };

  stage(0, 0);
  __syncthreads();
  int cur = 0;
  for (int k0 = 0; k0 < K; k0 += 32) {
    if (k0 + 32 < K) stage(cur ^ 1, k0 + 32);  // loads fly under this step's compute
    short8 af[4], bfr[4];
#pragma unroll
    for (int i = 0; i < 4; ++i) {
      af[i] = *(const short8*)(As[cur] + (wr * 64 + i * 16 + lr) * 32 + g * 8);
      bfr[i] = *(const short8*)(Bs[cur] + (wc * 64 + i * 16 + lr) * 32 + g * 8);
    }
#pragma unroll
    for (int mi = 0; mi < 4; ++mi)
#pragma unroll
      for (int ni = 0; ni < 4; ++ni)
        acc[mi][ni] = __builtin_amdgcn_mfma_f32_16x16x32_bf16(af[mi], bfr[ni], acc[mi][ni], 0, 0, 0);
    __syncthreads();  // compiler drains vmcnt here -> prefetched buffer ready
    cur ^= 1;
  }
#pragma unroll
  for (int mi = 0; mi < 4; ++mi)
#pragma unroll
    for (int ni = 0; ni < 4; ++ni) {
      int row = m0 + wr * 64 + mi * 16 + g * 4;
      int col = n0 + wc * 64 + ni * 16 + lr;
#pragma unroll
      for (int r = 0; r < 4; ++r)
        C[(size_t)(row + r) * N + col] = acc[mi][ni][r];
    }
}

// WT[n][k] = bf16(W[k][n]); W has 2048 rows, N cols; WT has ld 2048.
__global__ __launch_bounds__(256) void transpose_cvt(const float* __restrict__ W,
                                                     short* __restrict__ WT, int N) {
  __shared__ float tile[32][33];
  int tx = threadIdx.x, ty = threadIdx.y;
  int c0 = blockIdx.x * 32, r0 = blockIdx.y * 32;
#pragma unroll
  for (int i = 0; i < 4; ++i)
    tile[ty + i * 8][tx] = W[(size_t)(r0 + ty + i * 8) * N + c0 + tx];
  __syncthreads();
#pragma unroll
  for (int i = 0; i < 4; ++i)
    WT[(size_t)(c0 + ty + i * 8) * 2048 + r0 + tx] = f2bf(tile[tx][ty + i * 8]);
}

__global__ __launch_bounds__(256) void cvt_x(const float* __restrict__ x,
                                             short* __restrict__ xb, int n4) {
  int i = blockIdx.x * 256 + threadIdx.x;
  if (i >= n4) return;
  float4 v = ((const float4*)x)[i];
  short4v o;
  o.x = f2bf(v.x); o.y = f2bf(v.y); o.z = f2bf(v.z); o.w = f2bf(v.w);
  ((short4v*)xb)[i] = o;
}

// one wave per (t, u) with u in [0,20): u<16 -> q head u, else kv head u-16
// q is additionally pre-scaled by 1/sqrt(D)*log2(e) so attn works in log2 domain.
__global__ __launch_bounds__(256) void qk_post(const float* __restrict__ qkv,
                                               const float* __restrict__ cosb,
                                               const float* __restrict__ sinb,
                                               float* __restrict__ outPK,
                                               short* __restrict__ qb,
                                               short* __restrict__ kb) {
  int gw = (blockIdx.x * 256 + threadIdx.x) >> 6;
  int l = threadIdx.x & 63;
  int t = gw / 20, u = gw - t * 20;
  if (t >= 2048) return;
  float c = cosb[t * 64 + l], s = sinb[t * 64 + l];
  const float* src = qkv + (size_t)t * 3072 + (u < 16 ? u * 128 : 2048 + (u - 16) * 128);
  float x1 = src[l], x2 = src[64 + l];
  float lo = x1 * c + x2 * s;
  float hi = x2 * c - x1 * s;
  float ss = lo * lo + hi * hi;
#pragma unroll
  for (int d = 1; d < 64; d <<= 1) ss += __shfl_xor(ss, d, 64);
  float r = rsqrtf(ss * (1.0f / 128.0f) + 1e-6f) * 1.2f;
  if (u < 16) {
    const float SCQ = 0.08838834764831845f * 1.4426950408889634f;
    float rq = r * SCQ;
    size_t b = ((size_t)u * 2048 + t) * 128;
    qb[b + l] = f2bf(lo * rq);
    qb[b + 64 + l] = f2bf(hi * rq);
  } else {
    lo *= r; hi *= r;
    int kvh = u - 16;
    size_t b = ((size_t)(2048 + t) * 4 + kvh) * 128;
    outPK[b + l] = lo;
    outPK[b + 64 + l] = hi;
    size_t b2 = ((size_t)kvh * 4096 + 2048 + t) * 128;
    kb[b2 + l] = f2bf(lo);
    kb[b2 + 64 + l] = f2bf(hi);
  }
}

// one wave per (t, kv)
__global__ __launch_bounds__(256) void v_gate(const float* __restrict__ qkv,
                                              const float* __restrict__ x,
                                              const float* __restrict__ ve,
                                              const float* __restrict__ Wg,
                                              float* __restrict__ outPV,
                                              short* __restrict__ vbT) {
  int gw = (blockIdx.x * 256 + threadIdx.x) >> 6;
  int l = threadIdx.x & 63;
  int t = gw >> 2, kv = gw & 3;
  float z = 0.f;
#pragma unroll
  for (int j = 0; j < 12; ++j) z += x[(size_t)t * 2048 + j] * Wg[j * 4 + kv];
  float gate = 3.0f / (1.0f + expf(-z));
  const float* vr = qkv + (size_t)t * 3072 + 2560 + kv * 128;
  const float* vei = ve + (size_t)t * 512 + kv * 128;
  float v0 = vr[l] + gate * vei[l];
  float v1 = vr[64 + l] + gate * vei[64 + l];
  size_t b = ((size_t)(2048 + t) * 4 + kv) * 128;
  outPV[b + l] = v0;
  outPV[b + 64 + l] = v1;
  vbT[((size_t)kv * 128 + l) * 4096 + 2048 + t] = f2bf(v0);
  vbT[((size_t)kv * 128 + 64 + l) * 4096 + 2048 + t] = f2bf(v1);
}

__global__ __launch_bounds__(256) void past_copy(const float* __restrict__ pk,
                                                 const float* __restrict__ pv,
                                                 float* __restrict__ outPK,
                                                 float* __restrict__ outPV,
                                                 short* __restrict__ kb,
                                                 short* __restrict__ vbT) {
  int i = blockIdx.x * 256 + threadIdx.x;  // 0..1048575
  int d = i & 127, kv = (i >> 7) & 3, s = i >> 9;
  float a = pk[i], b = pv[i];
  outPK[i] = a;
  outPV[i] = b;
  kb[((size_t)kv * 4096 + s) * 128 + d] = f2bf(a);
  vbT[((size_t)kv * 128 + d) * 4096 + s] = f2bf(b);
}

// flash attention, 4-way key-split: grid 512 = 8 qb x 16 h x 4 cls.
// Block: 8 waves x 32 q (q-chunk of 256). K,V double-buffered in LDS
// (XOR-swizzled via pre-swizzled source). 80KB LDS -> 2 blocks/CU = 4 waves/SIMD.
// Block pairing: first 256 blocks qbi 7..4 (heavy), second 256 qbi 0..3 (light),
// so each CU's pair sums to equal work. Swapped QK^T, in-lane softmax, defer-max,
// per-wave 2KB P buffer. Writes normalized partial O (f16) + (m,l); merged later.
__global__ __launch_bounds__(512, 4) void attn(const short* __restrict__ qb,
                                               const short* __restrict__ kb,
                                               const short* __restrict__ vbT,
                                               short* __restrict__ Po,
                                               float* __restrict__ ml) {
  extern __shared__ __attribute__((aligned(16))) short smem[];
  short* Ks = smem;           // [2][64][128] shorts, swizzled (bytes 0..32K)
  short* Vs = smem + 16384;   // [2][128][64] shorts, swizzled (bytes 32K..64K)
  const int tid = threadIdx.x, w = tid >> 6, l = tid & 63;
  const int g = l >> 4, lr = l & 15;
  const int lid = blockIdx.x;
  const int qbi = (lid < 256) ? (7 - (lid >> 6)) : ((lid - 256) >> 6);
  const int sub = lid & 63;
  const int h = sub >> 2, cls = sub & 3;
  const int kv = h >> 2;
  const int qw = qbi * 256 + w * 32;
  char* Pw = (char*)smem + 65536 + w * 2048;  // per-wave P: [16 q][64 k] bf16, swizzled
  const short* gK = kb + (size_t)kv * 4096 * 128;
  const short* gV = vbT + (size_t)kv * 128 * 4096;
  const int nT = 36 + 4 * qbi;            // causal 64-key tiles for this q-chunk
  const int cnt = (nT - cls + 3) >> 2;    // tiles of this class

  short8 aq[2][4];
#pragma unroll
  for (int u = 0; u < 2; ++u)
#pragma unroll
    for (int c4 = 0; c4 < 4; ++c4)
      aq[u][c4] = *(const short8*)(qb + ((size_t)(h * 2048 + qw + u * 16 + lr)) * 128 + c4 * 32 + g * 8);

  float m_r[2] = {-INFINITY, -INFINITY};
  float l_r[2] = {0.f, 0.f};
  f32x4 o[2][8] = {};

  auto stageK = [&](int buf, int s0) {
#pragma unroll
    for (int it = 0; it < 2; ++it) {
      int idx = it * 512 + tid;            // 16B unit within 16KB tile
      int row = idx >> 4;                  // 0..63 (s)
      int colB = (idx & 15) * 16;          // byte col 0..240
      int scol = colB ^ ((row & 7) << 4);  // inverse-swizzle the SOURCE
      gload_lds16(gK + (size_t)(s0 + row) * 128 + (scol >> 1),
                  Ks + buf * 8192 + (it * 512 + w * 64) * 8);
    }
  };
  auto stageV = [&](int buf, int s0) {
#pragma unroll
    for (int it = 0; it < 2; ++it) {
      int idx = it * 512 + tid;
      int row = idx >> 3;                  // 0..127 (d)
      int colB = (idx & 7) * 16;           // byte col 0..112
      int scol = colB ^ ((row & 7) << 4);
      gload_lds16(gV + (size_t)row * 4096 + s0 + (scol >> 1),
                  Vs + buf * 8192 + (it * 512 + w * 64) * 8);
    }
  };

  stageK(0, cls * 64);
  stageV(0, cls * 64);
  __syncthreads();
  int cur = 0;
  for (int i = 0; i < cnt; ++i) {
    const int s0 = (cls + 4 * i) * 64;
    if (i + 1 < cnt) {
      stageK(cur ^ 1, s0 + 256);
      stageV(cur ^ 1, s0 + 256);
    }
    // swapped QK^T, both q-halves share every K fragment
    f32x4 sc[2][4] = {};
    __builtin_amdgcn_s_setprio(1);
#pragma unroll
    for (int cc = 0; cc < 4; ++cc) {
      const int rb = cur * 8192 + (cc * 16 + lr) * 128;
      short8 bk[4];
#pragma unroll
      for (int c4 = 0; c4 < 4; ++c4)
        bk[c4] = *(const short8*)(Ks + rb + (((c4 * 64 + g * 16) ^ ((lr & 7) << 4)) >> 1));
#pragma unroll
      for (int c4 = 0; c4 < 4; ++c4) {
        sc[0][cc] = __builtin_amdgcn_mfma_f32_16x16x32_bf16(bk[c4], aq[0][c4], sc[0][cc], 0, 0, 0);
        sc[1][cc] = __builtin_amdgcn_mfma_f32_16x16x32_bf16(bk[c4], aq[1][c4], sc[1][cc], 0, 0, 0);
      }
    }
    __builtin_amdgcn_s_setprio(0);
    if (s0 + 63 > 2048 + qw) {  // only diagonal/tail tiles mask
#pragma unroll
      for (int u = 0; u < 2; ++u)
#pragma unroll
        for (int cc = 0; cc < 4; ++cc)
#pragma unroll
          for (int r = 0; r < 4; ++r)
            sc[u][cc][r] = (s0 + cc * 16 + g * 4 + r <= 2048 + qw + u * 16 + lr)
                               ? sc[u][cc][r] : -INFINITY;
    }
    short8 ap[2][2];
#pragma unroll
    for (int u = 0; u < 2; ++u) {
      float pmax = -INFINITY;
#pragma unroll
      for (int cc = 0; cc < 4; ++cc) {
        float a = fmaxf(fmaxf(sc[u][cc][0], sc[u][cc][1]), fmaxf(sc[u][cc][2], sc[u][cc][3]));
        pmax = fmaxf(pmax, a);
      }
      if (!__all(pmax - m_r[u] <= 8.0f)) {  // defer-max
        float tm = fmaxf(pmax, __shfl_xor(pmax, 16, 64));
        tm = fmaxf(tm, __shfl_xor(tm, 32, 64));
        float mn = fmaxf(m_r[u], tm);
        float corr = exp2f(m_r[u] - mn);
        m_r[u] = mn;
        l_r[u] *= corr;
        float co[4];
#pragma unroll
        for (int r = 0; r < 4; ++r) co[r] = __shfl(corr, (l & 48) | (g * 4 + r), 64);
#pragma unroll
        for (int d8 = 0; d8 < 8; ++d8) {
          f32x4 tt = o[u][d8];
#pragma unroll
          for (int r = 0; r < 4; ++r) tt[r] *= co[r];
          o[u][d8] = tt;
        }
      }
      float ps = 0.f;
#pragma unroll
      for (int cc = 0; cc < 4; ++cc) {
        float p0 = exp2f(sc[u][cc][0] - m_r[u]);
        float p1 = exp2f(sc[u][cc][1] - m_r[u]);
        float p2 = exp2f(sc[u][cc][2] - m_r[u]);
        float p3 = exp2f(sc[u][cc][3] - m_r[u]);
        ps += (p0 + p1) + (p2 + p3);
        unsigned pk0 = cvt_pk_bf16(p0, p1);
        unsigned pk1 = cvt_pk_bf16(p2, p3);
        int off8 = (lr * 128 + cc * 32 + g * 8) ^ ((lr & 7) << 4);
        unsigned long long pq = (unsigned long long)pk0 | ((unsigned long long)pk1 << 32);
        *(unsigned long long*)(Pw + off8) = pq;
      }
      l_r[u] += ps;
#pragma unroll
      for (int ks = 0; ks < 2; ++ks)
        ap[u][ks] = *(const short8*)(Pw + ((lr * 128 + ks * 64 + g * 16) ^ ((lr & 7) << 4)));
    }
    // PV: both q-halves share every V fragment
    __builtin_amdgcn_s_setprio(1);
#pragma unroll
    for (int d8 = 0; d8 < 8; ++d8) {
      const int rb = cur * 8192 + (d8 * 16 + lr) * 64;
      short8 bv0 = *(const short8*)(Vs + rb + (((0 * 64 + g * 16) ^ ((lr & 7) << 4)) >> 1));
      short8 bv1 = *(const short8*)(Vs + rb + (((1 * 64 + g * 16) ^ ((lr & 7) << 4)) >> 1));
      o[0][d8] = __builtin_amdgcn_mfma_f32_16x16x32_bf16(ap[0][0], bv0, o[0][d8], 0, 0, 0);
      o[0][d8] = __builtin_amdgcn_mfma_f32_16x16x32_bf16(ap[0][1], bv1, o[0][d8], 0, 0, 0);
      o[1][d8] = __builtin_amdgcn_mfma_f32_16x16x32_bf16(ap[1][0], bv0, o[1][d8], 0, 0, 0);
      o[1][d8] = __builtin_amdgcn_mfma_f32_16x16x32_bf16(ap[1][1], bv1, o[1][d8], 0, 0, 0);
    }
    __builtin_amdgcn_s_setprio(0);
    __syncthreads();
    cur ^= 1;
  }
  // epilogue: normalize per class, store f16 partial + (m, l)
#pragma unroll
  for (int u = 0; u < 2; ++u) {
    float ls = l_r[u];
    ls += __shfl_xor(ls, 16, 64);
    ls += __shfl_xor(ls, 32, 64);
    float inv = 1.0f / ls;
    float invo[4];
#pragma unroll
    for (int r = 0; r < 4; ++r) invo[r] = __shfl(inv, (l & 48) | (g * 4 + r), 64);
#pragma unroll
    for (int d8 = 0; d8 < 8; ++d8)
#pragma unroll
      for (int r = 0; r < 4; ++r)
        Po[((size_t)(cls * 16 + h) * 2048 + qw + u * 16 + g * 4 + r) * 128 + d8 * 16 + lr] =
            f2h(o[u][d8][r] * invo[r]);
    if (g == 0) {
      float2 v;
      v.x = m_r[u];
      v.y = ls;
      ((float2*)ml)[(size_t)(cls * 16 + h) * 2048 + qw + u * 16 + lr] = v;
    }
  }
}

// merge 4 key-split partials -> ya (bf16). one thread per (q, h, 8-d chunk).
__global__ __launch_bounds__(256) void attn_merge(const short* __restrict__ Po,
                                                  const float* __restrict__ ml,
                                                  short* __restrict__ ya) {
  int i = blockIdx.x * 256 + threadIdx.x;  // 0..524287
  int q = i >> 8, rem = i & 255, h = rem >> 4, oct = rem & 15;
  float mc[4], lc[4], m = -INFINITY;
#pragma unroll
  for (int c = 0; c < 4; ++c) {
    float2 v = ((const float2*)ml)[(size_t)(c * 16 + h) * 2048 + q];
    mc[c] = v.x; lc[c] = v.y;
    m = fmaxf(m, mc[c]);
  }
  float wsum = 0.f, acc[8] = {};
#pragma unroll
  for (int c = 0; c < 4; ++c) {
    float wc = lc[c] * exp2f(mc[c] - m);
    wsum += wc;
    short8 p = *(const short8*)(Po + ((size_t)(c * 16 + h) * 2048 + q) * 128 + oct * 8);
#pragma unroll
    for (int j = 0; j < 8; ++j) acc[j] += wc * h2f(p[j]);
  }
  float inv = 1.0f / wsum;
  short8 ov;
#pragma unroll
  for (int j = 0; j < 8; ++j) ov[j] = f2bf(acc[j] * inv);
  *(short8*)(ya + (size_t)q * 2048 + h * 128 + oct * 8) = ov;
}

extern "C" void kernel_launch(void* const* d_in, const int* in_sizes, int n_in,
                              void* d_out, int out_size, void* d_ws, size_t ws_size,
                              hipStream_t stream) {
  const float* x = (const float*)d_in[0];
  const float* ve = (const float*)d_in[1];
  const float* cosb = (const float*)d_in[2];
  const float* sinb = (const float*)d_in[3];
  const float* past_key = (const float*)d_in[4];
  const float* past_value = (const float*)d_in[5];
  const float* Wq = (const float*)d_in[6];
  const float* Wk = (const float*)d_in[7];
  const float* Wv = (const float*)d_in[8];
  const float* Wo = (const float*)d_in[9];
  const float* Wg = (const float*)d_in[10];

  float* outY = (float*)d_out;          // 2048*2048
  float* outPK = outY + 4194304;        // 4096*4*128
  float* outPV = outPK + 2097152;       // 4096*4*128

  short* base = (short*)d_ws;
  short* WToT = base;                               // 2048*2048 bf16 (live to the end)
  short* WTqkv = base + 4194304;                    // 3072*2048 bf16  (dead after gemm1)
  short* xb = WTqkv + (size_t)6291456;              // 2048*2048 bf16  (dead after gemm1)
  float* qkv = (float*)(xb + (size_t)4194304);      // 2048*3072 f32   (dead after v_gate)
  short* qb = (short*)(qkv + (size_t)6291456);      // 16*2048*128 bf16
  short* kb = qb + (size_t)4194304;                 // 4*4096*128 bf16
  short* vbT = kb + (size_t)2097152;                // 4*128*4096 bf16 (transposed)
  short* ya = vbT + (size_t)2097152;                // 2048*2048 bf16
  // attn partials alias the dead WTqkv/xb/qkv pool:
  short* Po = WTqkv;                                // 4*16*2048*128 f16 = 16777216 shorts
  float* mlb = (float*)(base + 20971520);           // 4*16*2048 float2 = 1048576 floats

  static bool attr_set = false;
  if (!attr_set) {
    (void)hipFuncSetAttribute((const void*)attn,
                              hipFuncAttributeMaxDynamicSharedMemorySize, 81920);
    attr_set = true;
  }

  cvt_x<<<4096, 256, 0, stream>>>(x, xb, 1048576);
  dim3 tb(32, 8);
  transpose_cvt<<<dim3(64, 64), tb, 0, stream>>>(Wq, WTqkv, 2048);
  transpose_cvt<<<dim3(16, 64), tb, 0, stream>>>(Wk, WTqkv + (size_t)2048 * 2048, 512);
  transpose_cvt<<<dim3(16, 64), tb, 0, stream>>>(Wv, WTqkv + (size_t)2560 * 2048, 512);
  transpose_cvt<<<dim3(64, 64), tb, 0, stream>>>(Wo, WToT, 2048);

  gemm_bf16<<<dim3(24, 16), 256, 0, stream>>>(xb, WTqkv, qkv, 2048, 3072, 2048);

  qk_post<<<10240, 256, 0, stream>>>(qkv, cosb, sinb, outPK, qb, kb);
  v_gate<<<2048, 256, 0, stream>>>(qkv, x, ve, Wg, outPV, vbT);
  past_copy<<<4096, 256, 0, stream>>>(past_key, past_value, outPK, outPV, kb, vbT);

  attn<<<512, 512, 81920, stream>>>(qb, kb, vbT, Po, mlb);
  attn_merge<<<2048, 256, 0, stream>>>(Po, mlb, ya);

  gemm_bf16<<<dim3(16, 16), 256, 0, stream>>>(ya, WToT, outY, 2048, 2048, 2048);
}

// Round 6
// 212.950 us; speedup vs baseline: 1.6226x; 1.6226x over previous
//
#include <hip/hip_runtime.h>
#include <hip/hip_bf16.h>
#include <math.h>

typedef __attribute__((ext_vector_type(8))) short short8;
typedef __attribute__((ext_vector_type(4))) short short4v;
typedef __attribute__((ext_vector_type(4))) float f32x4;

#define DEV __device__ __forceinline__

DEV short f2bf(float f) {
  unsigned u = __builtin_bit_cast(unsigned, f);
  unsigned r = (u + 0x7FFFu + ((u >> 16) & 1u)) >> 16;
  return (short)r;
}

DEV short f2h(float f) {
  _Float16 h = (_Float16)f;
  return __builtin_bit_cast(short, h);
}

DEV float h2f(short s) {
  return (float)__builtin_bit_cast(_Float16, s);
}

DEV unsigned cvt_pk_bf16(float lo, float hi) {
  unsigned r;
  asm("v_cvt_pk_bf16_f32 %0, %1, %2" : "=v"(r) : "v"(lo), "v"(hi));
  return r;
}

DEV void gload_lds16(const void* g, void* l) {
  __builtin_amdgcn_global_load_lds((const __attribute__((address_space(1))) void*)g,
                                   (__attribute__((address_space(3))) void*)l, 16, 0, 0);
}

// C[M x N] (f32, row-major) = A[M x K] (bf16, row-major) * BT[N x K]^T (bf16 row-major N x K)
// 2-phase double-buffered: prefetch K-step k+1 issued BEFORE compute of k; one barrier/step.
__global__ __launch_bounds__(256) void gemm_bf16(const short* __restrict__ A,
                                                 const short* __restrict__ BT,
                                                 float* __restrict__ C,
                                                 int M, int N, int K) {
  __shared__ __attribute__((aligned(16))) short As[2][128 * 32];
  __shared__ __attribute__((aligned(16))) short Bs[2][128 * 32];
  const int tid = threadIdx.x;
  const int w = tid >> 6, l = tid & 63;
  const int g = l >> 4, lr = l & 15;
  const int m0 = blockIdx.y * 128, n0 = blockIdx.x * 128;
  const int wr = w >> 1, wc = w & 1;
  const int q0 = w * 2, q1 = w * 2 + 1;
  const int e0 = q0 * 512 + l * 8, e1 = q1 * 512 + l * 8;
  const int ra = e0 >> 5, ka = e0 & 31;
  const int rb_ = e1 >> 5, kb_ = e1 & 31;
  f32x4 acc[4][4] = {};

  auto stage = [&](int buf, int k0) {
    gload_lds16(A + (size_t)(m0 + ra) * K + k0 + ka, As[buf] + q0 * 512);
    gload_lds16(BT + (size_t)(n0 + ra) * K + k0 + ka, Bs[buf] + q0 * 512);
    gload_lds16(A + (size_t)(m0 + rb_) * K + k0 + kb_, As[buf] + q1 * 512);
    gload_lds16(BT + (size_t)(n0 + rb_) * K + k0 + kb_, Bs[buf] + q1 * 512);
  };

  stage(0, 0);
  __syncthreads();
  int cur = 0;
  for (int k0 = 0; k0 < K; k0 += 32) {
    if (k0 + 32 < K) stage(cur ^ 1, k0 + 32);  // loads fly under this step's compute
    short8 af[4], bfr[4];
#pragma unroll
    for (int i = 0; i < 4; ++i) {
      af[i] = *(const short8*)(As[cur] + (wr * 64 + i * 16 + lr) * 32 + g * 8);
      bfr[i] = *(const short8*)(Bs[cur] + (wc * 64 + i * 16 + lr) * 32 + g * 8);
    }
#pragma unroll
    for (int mi = 0; mi < 4; ++mi)
#pragma unroll
      for (int ni = 0; ni < 4; ++ni)
        acc[mi][ni] = __builtin_amdgcn_mfma_f32_16x16x32_bf16(af[mi], bfr[ni], acc[mi][ni], 0, 0, 0);
    __syncthreads();  // compiler drains vmcnt here -> prefetched buffer ready
    cur ^= 1;
  }
#pragma unroll
  for (int mi = 0; mi < 4; ++mi)
#pragma unroll
    for (int ni = 0; ni < 4; ++ni) {
      int row = m0 + wr * 64 + mi * 16 + g * 4;
      int col = n0 + wc * 64 + ni * 16 + lr;
#pragma unroll
      for (int r = 0; r < 4; ++r)
        C[(size_t)(row + r) * N + col] = acc[mi][ni][r];
    }
}

// WT[n][k] = bf16(W[k][n]); W has 2048 rows, N cols; WT has ld 2048.
__global__ __launch_bounds__(256) void transpose_cvt(const float* __restrict__ W,
                                                     short* __restrict__ WT, int N) {
  __shared__ float tile[32][33];
  int tx = threadIdx.x, ty = threadIdx.y;
  int c0 = blockIdx.x * 32, r0 = blockIdx.y * 32;
#pragma unroll
  for (int i = 0; i < 4; ++i)
    tile[ty + i * 8][tx] = W[(size_t)(r0 + ty + i * 8) * N + c0 + tx];
  __syncthreads();
#pragma unroll
  for (int i = 0; i < 4; ++i)
    WT[(size_t)(c0 + ty + i * 8) * 2048 + r0 + tx] = f2bf(tile[tx][ty + i * 8]);
}

__global__ __launch_bounds__(256) void cvt_x(const float* __restrict__ x,
                                             short* __restrict__ xb, int n4) {
  int i = blockIdx.x * 256 + threadIdx.x;
  if (i >= n4) return;
  float4 v = ((const float4*)x)[i];
  short4v o;
  o.x = f2bf(v.x); o.y = f2bf(v.y); o.z = f2bf(v.z); o.w = f2bf(v.w);
  ((short4v*)xb)[i] = o;
}

// one wave per (t, u) with u in [0,20): u<16 -> q head u, else kv head u-16
// q is additionally pre-scaled by 1/sqrt(D)*log2(e) so attn works in log2 domain.
__global__ __launch_bounds__(256) void qk_post(const float* __restrict__ qkv,
                                               const float* __restrict__ cosb,
                                               const float* __restrict__ sinb,
                                               float* __restrict__ outPK,
                                               short* __restrict__ qb,
                                               short* __restrict__ kb) {
  int gw = (blockIdx.x * 256 + threadIdx.x) >> 6;
  int l = threadIdx.x & 63;
  int t = gw / 20, u = gw - t * 20;
  if (t >= 2048) return;
  float c = cosb[t * 64 + l], s = sinb[t * 64 + l];
  const float* src = qkv + (size_t)t * 3072 + (u < 16 ? u * 128 : 2048 + (u - 16) * 128);
  float x1 = src[l], x2 = src[64 + l];
  float lo = x1 * c + x2 * s;
  float hi = x2 * c - x1 * s;
  float ss = lo * lo + hi * hi;
#pragma unroll
  for (int d = 1; d < 64; d <<= 1) ss += __shfl_xor(ss, d, 64);
  float r = rsqrtf(ss * (1.0f / 128.0f) + 1e-6f) * 1.2f;
  if (u < 16) {
    const float SCQ = 0.08838834764831845f * 1.4426950408889634f;
    float rq = r * SCQ;
    size_t b = ((size_t)u * 2048 + t) * 128;
    qb[b + l] = f2bf(lo * rq);
    qb[b + 64 + l] = f2bf(hi * rq);
  } else {
    lo *= r; hi *= r;
    int kvh = u - 16;
    size_t b = ((size_t)(2048 + t) * 4 + kvh) * 128;
    outPK[b + l] = lo;
    outPK[b + 64 + l] = hi;
    size_t b2 = ((size_t)kvh * 4096 + 2048 + t) * 128;
    kb[b2 + l] = f2bf(lo);
    kb[b2 + 64 + l] = f2bf(hi);
  }
}

// one wave per (t, kv)
__global__ __launch_bounds__(256) void v_gate(const float* __restrict__ qkv,
                                              const float* __restrict__ x,
                                              const float* __restrict__ ve,
                                              const float* __restrict__ Wg,
                                              float* __restrict__ outPV,
                                              short* __restrict__ vbT) {
  int gw = (blockIdx.x * 256 + threadIdx.x) >> 6;
  int l = threadIdx.x & 63;
  int t = gw >> 2, kv = gw & 3;
  float z = 0.f;
#pragma unroll
  for (int j = 0; j < 12; ++j) z += x[(size_t)t * 2048 + j] * Wg[j * 4 + kv];
  float gate = 3.0f / (1.0f + expf(-z));
  const float* vr = qkv + (size_t)t * 3072 + 2560 + kv * 128;
  const float* vei = ve + (size_t)t * 512 + kv * 128;
  float v0 = vr[l] + gate * vei[l];
  float v1 = vr[64 + l] + gate * vei[64 + l];
  size_t b = ((size_t)(2048 + t) * 4 + kv) * 128;
  outPV[b + l] = v0;
  outPV[b + 64 + l] = v1;
  vbT[((size_t)kv * 128 + l) * 4096 + 2048 + t] = f2bf(v0);
  vbT[((size_t)kv * 128 + 64 + l) * 4096 + 2048 + t] = f2bf(v1);
}

__global__ __launch_bounds__(256) void past_copy(const float* __restrict__ pk,
                                                 const float* __restrict__ pv,
                                                 float* __restrict__ outPK,
                                                 float* __restrict__ outPV,
                                                 short* __restrict__ kb,
                                                 short* __restrict__ vbT) {
  int i = blockIdx.x * 256 + threadIdx.x;  // 0..1048575
  int d = i & 127, kv = (i >> 7) & 3, s = i >> 9;
  float a = pk[i], b = pv[i];
  outPK[i] = a;
  outPV[i] = b;
  kb[((size_t)kv * 4096 + s) * 128 + d] = f2bf(a);
  vbT[((size_t)kv * 128 + d) * 4096 + s] = f2bf(b);
}

// flash attention, 4-way key-split: grid 1024 = 16 qb x 16 h x 4 cls (LPT order).
// Block: 4 waves x 32 q (q-chunk of 128), keys = tiles tt==cls (mod 4) of the
// causal range. K/V double-buffered LDS (XOR-swizzled via pre-swizzled source),
// swapped QK^T, in-lane softmax, defer-max, per-wave 2KB P buffer (b64 writes).
// Writes normalized partial O (f16) + (m,l) per (cls, h, q); merged by attn_merge.
__global__ __launch_bounds__(256, 2) void attn(const short* __restrict__ qb,
                                               const short* __restrict__ kb,
                                               const short* __restrict__ vbT,
                                               short* __restrict__ Po,
                                               float* __restrict__ ml) {
  extern __shared__ __attribute__((aligned(16))) short smem[];
  short* Ks = smem;           // [2][64][128] shorts, swizzled
  short* Vs = smem + 16384;   // [2][128][64] shorts, swizzled
  const int tid = threadIdx.x, w = tid >> 6, l = tid & 63;
  const int g = l >> 4, lr = l & 15;
  const int lid = blockIdx.x;
  const int qbi = 15 - (lid >> 6);        // LPT: largest q-chunks (most tiles) first
  const int sub = lid & 63;
  const int h = sub >> 2, cls = sub & 3;
  const int kv = h >> 2;
  const int qw = qbi * 128 + w * 32;      // wave's first q row
  char* Pw = (char*)(smem + 32768) + w * 2048;  // per-wave P: [16 q][64 k] bf16, swizzled
  const short* gK = kb + (size_t)kv * 4096 * 128;
  const short* gV = vbT + (size_t)kv * 128 * 4096;
  const int nT = 34 + 2 * qbi;            // total causal tiles for this q-chunk
  const int cnt = (nT - cls + 3) >> 2;    // tiles of this class

  short8 aq[2][4];
#pragma unroll
  for (int u = 0; u < 2; ++u)
#pragma unroll
    for (int c4 = 0; c4 < 4; ++c4)
      aq[u][c4] = *(const short8*)(qb + ((size_t)(h * 2048 + qw + u * 16 + lr)) * 128 + c4 * 32 + g * 8);

  float m_r[2] = {-INFINITY, -INFINITY};
  float l_r[2] = {0.f, 0.f};
  f32x4 o[2][8] = {};

  auto stageK = [&](int buf, int s0) {
#pragma unroll
    for (int it = 0; it < 4; ++it) {
      int idx = it * 256 + tid;
      int row = idx >> 4;
      int colB = (idx & 15) * 16;
      int scol = colB ^ ((row & 7) << 4);
      gload_lds16(gK + (size_t)(s0 + row) * 128 + (scol >> 1),
                  Ks + buf * 8192 + (it * 256 + w * 64) * 8);
    }
  };
  auto stageV = [&](int buf, int s0) {
#pragma unroll
    for (int it = 0; it < 4; ++it) {
      int idx = it * 256 + tid;
      int row = idx >> 3;
      int colB = (idx & 7) * 16;
      int scol = colB ^ ((row & 7) << 4);
      gload_lds16(gV + (size_t)row * 4096 + s0 + (scol >> 1),
                  Vs + buf * 8192 + (it * 256 + w * 64) * 8);
    }
  };

  stageK(0, cls * 64);
  stageV(0, cls * 64);
  __syncthreads();
  int cur = 0;
  for (int i = 0; i < cnt; ++i) {
    const int s0 = (cls + 4 * i) * 64;
    if (i + 1 < cnt) {
      stageK(cur ^ 1, s0 + 256);
      stageV(cur ^ 1, s0 + 256);
    }
    // swapped QK^T, both q-halves share every K fragment
    f32x4 sc[2][4] = {};
    __builtin_amdgcn_s_setprio(1);
#pragma unroll
    for (int cc = 0; cc < 4; ++cc) {
      const int rb = cur * 8192 + (cc * 16 + lr) * 128;
      short8 bk[4];
#pragma unroll
      for (int c4 = 0; c4 < 4; ++c4)
        bk[c4] = *(const short8*)(Ks + rb + (((c4 * 64 + g * 16) ^ ((lr & 7) << 4)) >> 1));
#pragma unroll
      for (int c4 = 0; c4 < 4; ++c4) {
        sc[0][cc] = __builtin_amdgcn_mfma_f32_16x16x32_bf16(bk[c4], aq[0][c4], sc[0][cc], 0, 0, 0);
        sc[1][cc] = __builtin_amdgcn_mfma_f32_16x16x32_bf16(bk[c4], aq[1][c4], sc[1][cc], 0, 0, 0);
      }
    }
    __builtin_amdgcn_s_setprio(0);
    if (s0 + 63 > 2048 + qw) {  // only diagonal/tail tiles mask
#pragma unroll
      for (int u = 0; u < 2; ++u)
#pragma unroll
        for (int cc = 0; cc < 4; ++cc)
#pragma unroll
          for (int r = 0; r < 4; ++r)
            sc[u][cc][r] = (s0 + cc * 16 + g * 4 + r <= 2048 + qw + u * 16 + lr)
                               ? sc[u][cc][r] : -INFINITY;
    }
    short8 ap[2][2];
#pragma unroll
    for (int u = 0; u < 2; ++u) {
      float pmax = -INFINITY;
#pragma unroll
      for (int cc = 0; cc < 4; ++cc) {
        float a = fmaxf(fmaxf(sc[u][cc][0], sc[u][cc][1]), fmaxf(sc[u][cc][2], sc[u][cc][3]));
        pmax = fmaxf(pmax, a);
      }
      if (!__all(pmax - m_r[u] <= 8.0f)) {  // defer-max
        float tm = fmaxf(pmax, __shfl_xor(pmax, 16, 64));
        tm = fmaxf(tm, __shfl_xor(tm, 32, 64));
        float mn = fmaxf(m_r[u], tm);
        float corr = exp2f(m_r[u] - mn);
        m_r[u] = mn;
        l_r[u] *= corr;
        float co[4];
#pragma unroll
        for (int r = 0; r < 4; ++r) co[r] = __shfl(corr, (l & 48) | (g * 4 + r), 64);
#pragma unroll
        for (int d8 = 0; d8 < 8; ++d8) {
          f32x4 tt = o[u][d8];
#pragma unroll
          for (int r = 0; r < 4; ++r) tt[r] *= co[r];
          o[u][d8] = tt;
        }
      }
      float ps = 0.f;
#pragma unroll
      for (int cc = 0; cc < 4; ++cc) {
        float p0 = exp2f(sc[u][cc][0] - m_r[u]);
        float p1 = exp2f(sc[u][cc][1] - m_r[u]);
        float p2 = exp2f(sc[u][cc][2] - m_r[u]);
        float p3 = exp2f(sc[u][cc][3] - m_r[u]);
        ps += (p0 + p1) + (p2 + p3);
        unsigned pk0 = cvt_pk_bf16(p0, p1);
        unsigned pk1 = cvt_pk_bf16(p2, p3);
        int off8 = (lr * 128 + cc * 32 + g * 8) ^ ((lr & 7) << 4);
        unsigned long long pq = (unsigned long long)pk0 | ((unsigned long long)pk1 << 32);
        *(unsigned long long*)(Pw + off8) = pq;
      }
      l_r[u] += ps;
#pragma unroll
      for (int ks = 0; ks < 2; ++ks)
        ap[u][ks] = *(const short8*)(Pw + ((lr * 128 + ks * 64 + g * 16) ^ ((lr & 7) << 4)));
    }
    // PV: both q-halves share every V fragment
    __builtin_amdgcn_s_setprio(1);
#pragma unroll
    for (int d8 = 0; d8 < 8; ++d8) {
      const int rb = cur * 8192 + (d8 * 16 + lr) * 64;
      short8 bv0 = *(const short8*)(Vs + rb + (((0 * 64 + g * 16) ^ ((lr & 7) << 4)) >> 1));
      short8 bv1 = *(const short8*)(Vs + rb + (((1 * 64 + g * 16) ^ ((lr & 7) << 4)) >> 1));
      o[0][d8] = __builtin_amdgcn_mfma_f32_16x16x32_bf16(ap[0][0], bv0, o[0][d8], 0, 0, 0);
      o[0][d8] = __builtin_amdgcn_mfma_f32_16x16x32_bf16(ap[0][1], bv1, o[0][d8], 0, 0, 0);
      o[1][d8] = __builtin_amdgcn_mfma_f32_16x16x32_bf16(ap[1][0], bv0, o[1][d8], 0, 0, 0);
      o[1][d8] = __builtin_amdgcn_mfma_f32_16x16x32_bf16(ap[1][1], bv1, o[1][d8], 0, 0, 0);
    }
    __builtin_amdgcn_s_setprio(0);
    __syncthreads();
    cur ^= 1;
  }
  // epilogue: normalize per class, store f16 partial + (m, l)
#pragma unroll
  for (int u = 0; u < 2; ++u) {
    float ls = l_r[u];
    ls += __shfl_xor(ls, 16, 64);
    ls += __shfl_xor(ls, 32, 64);
    float inv = 1.0f / ls;
    float invo[4];
#pragma unroll
    for (int r = 0; r < 4; ++r) invo[r] = __shfl(inv, (l & 48) | (g * 4 + r), 64);
#pragma unroll
    for (int d8 = 0; d8 < 8; ++d8)
#pragma unroll
      for (int r = 0; r < 4; ++r)
        Po[((size_t)(cls * 16 + h) * 2048 + qw + u * 16 + g * 4 + r) * 128 + d8 * 16 + lr] =
            f2h(o[u][d8][r] * invo[r]);
    if (g == 0) {
      float2 v;
      v.x = m_r[u];
      v.y = ls;
      ((float2*)ml)[(size_t)(cls * 16 + h) * 2048 + qw + u * 16 + lr] = v;
    }
  }
}

// merge 4 key-split partials -> ya (bf16). one thread per (q, h, 8-d chunk).
__global__ __launch_bounds__(256) void attn_merge(const short* __restrict__ Po,
                                                  const float* __restrict__ ml,
                                                  short* __restrict__ ya) {
  int i = blockIdx.x * 256 + threadIdx.x;  // 0..524287
  int q = i >> 8, rem = i & 255, h = rem >> 4, oct = rem & 15;
  float mc[4], lc[4], m = -INFINITY;
#pragma unroll
  for (int c = 0; c < 4; ++c) {
    float2 v = ((const float2*)ml)[(size_t)(c * 16 + h) * 2048 + q];
    mc[c] = v.x; lc[c] = v.y;
    m = fmaxf(m, mc[c]);
  }
  float wsum = 0.f, acc[8] = {};
#pragma unroll
  for (int c = 0; c < 4; ++c) {
    float wc = lc[c] * exp2f(mc[c] - m);
    wsum += wc;
    short8 p = *(const short8*)(Po + ((size_t)(c * 16 + h) * 2048 + q) * 128 + oct * 8);
#pragma unroll
    for (int j = 0; j < 8; ++j) acc[j] += wc * h2f(p[j]);
  }
  float inv = 1.0f / wsum;
  short8 ov;
#pragma unroll
  for (int j = 0; j < 8; ++j) ov[j] = f2bf(acc[j] * inv);
  *(short8*)(ya + (size_t)q * 2048 + h * 128 + oct * 8) = ov;
}

extern "C" void kernel_launch(void* const* d_in, const int* in_sizes, int n_in,
                              void* d_out, int out_size, void* d_ws, size_t ws_size,
                              hipStream_t stream) {
  const float* x = (const float*)d_in[0];
  const float* ve = (const float*)d_in[1];
  const float* cosb = (const float*)d_in[2];
  const float* sinb = (const float*)d_in[3];
  const float* past_key = (const float*)d_in[4];
  const float* past_value = (const float*)d_in[5];
  const float* Wq = (const float*)d_in[6];
  const float* Wk = (const float*)d_in[7];
  const float* Wv = (const float*)d_in[8];
  const float* Wo = (const float*)d_in[9];
  const float* Wg = (const float*)d_in[10];

  float* outY = (float*)d_out;          // 2048*2048
  float* outPK = outY + 4194304;        // 4096*4*128
  float* outPV = outPK + 2097152;       // 4096*4*128

  short* base = (short*)d_ws;
  short* WToT = base;                               // 2048*2048 bf16 (live to the end)
  short* WTqkv = base + 4194304;                    // 3072*2048 bf16  (dead after gemm1)
  short* xb = WTqkv + (size_t)6291456;              // 2048*2048 bf16  (dead after gemm1)
  float* qkv = (float*)(xb + (size_t)4194304);      // 2048*3072 f32   (dead after v_gate)
  short* qb = (short*)(qkv + (size_t)6291456);      // 16*2048*128 bf16
  short* kb = qb + (size_t)4194304;                 // 4*4096*128 bf16
  short* vbT = kb + (size_t)2097152;                // 4*128*4096 bf16 (transposed)
  short* ya = vbT + (size_t)2097152;                // 2048*2048 bf16
  // attn partials alias the dead WTqkv/xb/qkv pool:
  short* Po = WTqkv;                                // 4*16*2048*128 f16 = 16777216 shorts
  float* mlb = (float*)(base + 20971520);           // 4*16*2048 float2 = 1048576 floats

  static bool attr_set = false;
  if (!attr_set) {
    (void)hipFuncSetAttribute((const void*)attn,
                              hipFuncAttributeMaxDynamicSharedMemorySize, 73728);
    attr_set = true;
  }

  cvt_x<<<4096, 256, 0, stream>>>(x, xb, 1048576);
  dim3 tb(32, 8);
  transpose_cvt<<<dim3(64, 64), tb, 0, stream>>>(Wq, WTqkv, 2048);
  transpose_cvt<<<dim3(16, 64), tb, 0, stream>>>(Wk, WTqkv + (size_t)2048 * 2048, 512);
  transpose_cvt<<<dim3(16, 64), tb, 0, stream>>>(Wv, WTqkv + (size_t)2560 * 2048, 512);
  transpose_cvt<<<dim3(64, 64), tb, 0, stream>>>(Wo, WToT, 2048);

  gemm_bf16<<<dim3(24, 16), 256, 0, stream>>>(xb, WTqkv, qkv, 2048, 3072, 2048);

  qk_post<<<10240, 256, 0, stream>>>(qkv, cosb, sinb, outPK, qb, kb);
  v_gate<<<2048, 256, 0, stream>>>(qkv, x, ve, Wg, outPV, vbT);
  past_copy<<<4096, 256, 0, stream>>>(past_key, past_value, outPK, outPV, kb, vbT);

  attn<<<1024, 256, 73728, stream>>>(qb, kb, vbT, Po, mlb);
  attn_merge<<<2048, 256, 0, stream>>>(Po, mlb, ya);

  gemm_bf16<<<dim3(16, 16), 256, 0, stream>>>(ya, WToT, outY, 2048, 2048, 2048);
}

// Round 7
// 189.513 us; speedup vs baseline: 1.8233x; 1.1237x over previous
//
#include <hip/hip_runtime.h>
#include <hip/hip_bf16.h>
#include <math.h>

typedef __attribute__((ext_vector_type(8))) short short8;
typedef __attribute__((ext_vector_type(4))) short short4v;
typedef __attribute__((ext_vector_type(4))) float f32x4;

#define DEV __device__ __forceinline__

DEV short f2bf(float f) {
  unsigned u = __builtin_bit_cast(unsigned, f);
  unsigned r = (u + 0x7FFFu + ((u >> 16) & 1u)) >> 16;
  return (short)r;
}

DEV short f2h(float f) {
  _Float16 h = (_Float16)f;
  return __builtin_bit_cast(short, h);
}

DEV float h2f(short s) {
  return (float)__builtin_bit_cast(_Float16, s);
}

DEV unsigned cvt_pk_bf16(float lo, float hi) {
  unsigned r;
  asm("v_cvt_pk_bf16_f32 %0, %1, %2" : "=v"(r) : "v"(lo), "v"(hi));
  return r;
}

DEV void gload_lds16(const void* g, void* l) {
  __builtin_amdgcn_global_load_lds((const __attribute__((address_space(1))) void*)g,
                                   (__attribute__((address_space(3))) void*)l, 16, 0, 0);
}

// C[M x N] (f32) = A[M x K] (bf16) * BT[N x K]^T, BK=32, 2-phase dbuf + XCD swizzle.
__global__ __launch_bounds__(256) void gemm_bf16(const short* __restrict__ A,
                                                 const short* __restrict__ BT,
                                                 float* __restrict__ C,
                                                 int M, int N, int K) {
  __shared__ __attribute__((aligned(16))) short As[2][128 * 32];
  __shared__ __attribute__((aligned(16))) short Bs[2][128 * 32];
  const int tid = threadIdx.x;
  const int w = tid >> 6, l = tid & 63;
  const int g = l >> 4, lr = l & 15;
  // XCD-aware bijective swizzle (nwg % 8 == 0): 8 XCDs get contiguous chunks.
  int nbx = gridDim.x, nwg = nbx * gridDim.y;
  int flat = blockIdx.y * nbx + blockIdx.x;
  int qq = nwg >> 3;
  int f2 = (flat & 7) * qq + (flat >> 3);
  const int m0 = (f2 / nbx) * 128, n0 = (f2 % nbx) * 128;
  const int wr = w >> 1, wc = w & 1;
  const int q0 = w * 2, q1 = w * 2 + 1;
  const int e0 = q0 * 512 + l * 8, e1 = q1 * 512 + l * 8;
  const int ra = e0 >> 5, ka = e0 & 31;
  const int rb_ = e1 >> 5, kb_ = e1 & 31;
  f32x4 acc[4][4] = {};

  auto stage = [&](int buf, int k0) {
    gload_lds16(A + (size_t)(m0 + ra) * K + k0 + ka, As[buf] + q0 * 512);
    gload_lds16(BT + (size_t)(n0 + ra) * K + k0 + ka, Bs[buf] + q0 * 512);
    gload_lds16(A + (size_t)(m0 + rb_) * K + k0 + kb_, As[buf] + q1 * 512);
    gload_lds16(BT + (size_t)(n0 + rb_) * K + k0 + kb_, Bs[buf] + q1 * 512);
  };

  stage(0, 0);
  __syncthreads();
  int cur = 0;
  for (int k0 = 0; k0 < K; k0 += 32) {
    if (k0 + 32 < K) stage(cur ^ 1, k0 + 32);
    short8 af[4], bfr[4];
#pragma unroll
    for (int i = 0; i < 4; ++i) {
      af[i] = *(const short8*)(As[cur] + (wr * 64 + i * 16 + lr) * 32 + g * 8);
      bfr[i] = *(const short8*)(Bs[cur] + (wc * 64 + i * 16 + lr) * 32 + g * 8);
    }
#pragma unroll
    for (int mi = 0; mi < 4; ++mi)
#pragma unroll
      for (int ni = 0; ni < 4; ++ni)
        acc[mi][ni] = __builtin_amdgcn_mfma_f32_16x16x32_bf16(af[mi], bfr[ni], acc[mi][ni], 0, 0, 0);
    __syncthreads();
    cur ^= 1;
  }
#pragma unroll
  for (int mi = 0; mi < 4; ++mi)
#pragma unroll
    for (int ni = 0; ni < 4; ++ni) {
      int row = m0 + wr * 64 + mi * 16 + g * 4;
      int col = n0 + wc * 64 + ni * 16 + lr;
#pragma unroll
      for (int r = 0; r < 4; ++r)
        C[(size_t)(row + r) * N + col] = acc[mi][ni][r];
    }
}

// BK=64 variant for the 1-block/CU regime (gemm2): 64KB LDS dbuf, XOR-swizzled
// rows (pre-swizzled gload source + XOR read) -> 2-way conflicts, half the barriers.
__global__ __launch_bounds__(256) void gemm_bf16_k64(const short* __restrict__ A,
                                                     const short* __restrict__ BT,
                                                     float* __restrict__ C,
                                                     int M, int N, int K) {
  __shared__ __attribute__((aligned(16))) short As[2][128 * 64];
  __shared__ __attribute__((aligned(16))) short Bs[2][128 * 64];
  const int tid = threadIdx.x;
  const int w = tid >> 6, l = tid & 63;
  const int g = l >> 4, lr = l & 15;
  int nbx = gridDim.x, nwg = nbx * gridDim.y;
  int flat = blockIdx.y * nbx + blockIdx.x;
  int qq = nwg >> 3;
  int f2 = (flat & 7) * qq + (flat >> 3);
  const int m0 = (f2 / nbx) * 128, n0 = (f2 % nbx) * 128;
  const int wr = w >> 1, wc = w & 1;
  f32x4 acc[4][4] = {};

  auto stage = [&](int buf, int k0) {
#pragma unroll
    for (int it = 0; it < 4; ++it) {
      int idx = it * 256 + tid;            // 16B unit; 1024 units per 16KB tile
      int row = idx >> 3;                  // 0..127
      int colB = (idx & 7) * 16;           // 0..112
      int scol = colB ^ ((row & 7) << 4);  // inverse-swizzle the source
      gload_lds16(A + (size_t)(m0 + row) * K + k0 + (scol >> 1), As[buf] + idx * 8);
      gload_lds16(BT + (size_t)(n0 + row) * K + k0 + (scol >> 1), Bs[buf] + idx * 8);
    }
  };

  stage(0, 0);
  __syncthreads();
  int cur = 0;
  for (int k0 = 0; k0 < K; k0 += 64) {
    if (k0 + 64 < K) stage(cur ^ 1, k0 + 64);
#pragma unroll
    for (int ki = 0; ki < 2; ++ki) {
      short8 af[4], bfr[4];
#pragma unroll
      for (int i = 0; i < 4; ++i) {
        int off = ((wr * 64 + i * 16 + lr) * 128 + ((ki * 64 + g * 16) ^ ((lr & 7) << 4))) >> 1;
        int offb = ((wc * 64 + i * 16 + lr) * 128 + ((ki * 64 + g * 16) ^ ((lr & 7) << 4))) >> 1;
        af[i] = *(const short8*)(As[cur] + off);
        bfr[i] = *(const short8*)(Bs[cur] + offb);
      }
#pragma unroll
      for (int mi = 0; mi < 4; ++mi)
#pragma unroll
        for (int ni = 0; ni < 4; ++ni)
          acc[mi][ni] = __builtin_amdgcn_mfma_f32_16x16x32_bf16(af[mi], bfr[ni], acc[mi][ni], 0, 0, 0);
    }
    __syncthreads();
    cur ^= 1;
  }
#pragma unroll
  for (int mi = 0; mi < 4; ++mi)
#pragma unroll
    for (int ni = 0; ni < 4; ++ni) {
      int row = m0 + wr * 64 + mi * 16 + g * 4;
      int col = n0 + wc * 64 + ni * 16 + lr;
#pragma unroll
      for (int r = 0; r < 4; ++r)
        C[(size_t)(row + r) * N + col] = acc[mi][ni][r];
    }
}

// All four weight transposes in ONE launch. bx: [0,64) Wq, [64,80) Wk, [80,96) Wv, [96,160) Wo.
__global__ __launch_bounds__(256) void transpose_all(const float* __restrict__ Wq,
                                                     const float* __restrict__ Wk,
                                                     const float* __restrict__ Wv,
                                                     const float* __restrict__ Wo,
                                                     short* __restrict__ WTqkv,
                                                     short* __restrict__ WToT) {
  __shared__ float tile[32][33];
  int bx = blockIdx.x;
  const float* W;
  short* WT;
  int N, cb;
  if (bx < 64) { W = Wq; WT = WTqkv; N = 2048; cb = bx; }
  else if (bx < 80) { W = Wk; WT = WTqkv + (size_t)2048 * 2048; N = 512; cb = bx - 64; }
  else if (bx < 96) { W = Wv; WT = WTqkv + (size_t)2560 * 2048; N = 512; cb = bx - 80; }
  else { W = Wo; WT = WToT; N = 2048; cb = bx - 96; }
  int tx = threadIdx.x, ty = threadIdx.y;
  int c0 = cb * 32, r0 = blockIdx.y * 32;
#pragma unroll
  for (int i = 0; i < 4; ++i)
    tile[ty + i * 8][tx] = W[(size_t)(r0 + ty + i * 8) * N + c0 + tx];
  __syncthreads();
#pragma unroll
  for (int i = 0; i < 4; ++i)
    WT[(size_t)(c0 + ty + i * 8) * 2048 + r0 + tx] = f2bf(tile[tx][ty + i * 8]);
}

__global__ __launch_bounds__(256) void cvt_x(const float* __restrict__ x,
                                             short* __restrict__ xb, int n4) {
  int i = blockIdx.x * 256 + threadIdx.x;
  if (i >= n4) return;
  float4 v = ((const float4*)x)[i];
  short4v o;
  o.x = f2bf(v.x); o.y = f2bf(v.y); o.z = f2bf(v.z); o.w = f2bf(v.w);
  ((short4v*)xb)[i] = o;
}

// Fused qk_post + v_gate: one wave per (t, u), u in [0,24).
// u<16: q head (rope+rmsnorm, pre-scaled by 1/sqrt(D)*log2e); 16-19: k head;
// 20-23: v head (gate + ve). No scattered vbT writes (v_transpose handles that).
__global__ __launch_bounds__(256) void qkv_post(const float* __restrict__ qkv,
                                                const float* __restrict__ cosb,
                                                const float* __restrict__ sinb,
                                                const float* __restrict__ x,
                                                const float* __restrict__ ve,
                                                const float* __restrict__ Wg,
                                                float* __restrict__ outPK,
                                                float* __restrict__ outPV,
                                                short* __restrict__ qb,
                                                short* __restrict__ kb) {
  int gw = (blockIdx.x * 256 + threadIdx.x) >> 6;
  int l = threadIdx.x & 63;
  int t = gw / 24, u = gw - t * 24;
  if (t >= 2048) return;
  if (u < 20) {
    float c = cosb[t * 64 + l], s = sinb[t * 64 + l];
    const float* src = qkv + (size_t)t * 3072 + (u < 16 ? u * 128 : 2048 + (u - 16) * 128);
    float x1 = src[l], x2 = src[64 + l];
    float lo = x1 * c + x2 * s;
    float hi = x2 * c - x1 * s;
    float ss = lo * lo + hi * hi;
#pragma unroll
    for (int d = 1; d < 64; d <<= 1) ss += __shfl_xor(ss, d, 64);
    float r = rsqrtf(ss * (1.0f / 128.0f) + 1e-6f) * 1.2f;
    if (u < 16) {
      const float SCQ = 0.08838834764831845f * 1.4426950408889634f;
      float rq = r * SCQ;
      size_t b = ((size_t)u * 2048 + t) * 128;
      qb[b + l] = f2bf(lo * rq);
      qb[b + 64 + l] = f2bf(hi * rq);
    } else {
      lo *= r; hi *= r;
      int kvh = u - 16;
      size_t b = ((size_t)(2048 + t) * 4 + kvh) * 128;
      outPK[b + l] = lo;
      outPK[b + 64 + l] = hi;
      size_t b2 = ((size_t)kvh * 4096 + 2048 + t) * 128;
      kb[b2 + l] = f2bf(lo);
      kb[b2 + 64 + l] = f2bf(hi);
    }
  } else {
    int kv = u - 20;
    float z = 0.f;
#pragma unroll
    for (int j = 0; j < 12; ++j) z += x[(size_t)t * 2048 + j] * Wg[j * 4 + kv];
    float gate = 3.0f / (1.0f + expf(-z));
    const float* vr = qkv + (size_t)t * 3072 + 2560 + kv * 128;
    const float* vei = ve + (size_t)t * 512 + kv * 128;
    float v0 = vr[l] + gate * vei[l];
    float v1 = vr[64 + l] + gate * vei[64 + l];
    size_t b = ((size_t)(2048 + t) * 4 + kv) * 128;
    outPV[b + l] = v0;
    outPV[b + 64 + l] = v1;
  }
}

// past copy: coalesced only (vbT scatter removed; v_transpose handles it).
__global__ __launch_bounds__(256) void past_copy(const float* __restrict__ pk,
                                                 const float* __restrict__ pv,
                                                 float* __restrict__ outPK,
                                                 float* __restrict__ outPV,
                                                 short* __restrict__ kb) {
  int i = blockIdx.x * 256 + threadIdx.x;  // 0..1048575
  int d = i & 127, kv = (i >> 7) & 3, s = i >> 9;
  float a = pk[i], b = pv[i];
  outPK[i] = a;
  outPV[i] = b;
  kb[((size_t)kv * 4096 + s) * 128 + d] = f2bf(a);
}

// vbT[kv*128+d][s] = bf16(outPV viewed as [4096 s][512 c]) -- LDS-tiled transpose,
// fully coalesced both sides. grid (16, 128), block (32,8).
__global__ __launch_bounds__(256) void v_transpose(const float* __restrict__ PV,
                                                   short* __restrict__ vbT) {
  __shared__ float tile[32][33];
  int tx = threadIdx.x, ty = threadIdx.y;
  int c0 = blockIdx.x * 32, r0 = blockIdx.y * 32;
#pragma unroll
  for (int i = 0; i < 4; ++i)
    tile[ty + i * 8][tx] = PV[(size_t)(r0 + ty + i * 8) * 512 + c0 + tx];
  __syncthreads();
#pragma unroll
  for (int i = 0; i < 4; ++i)
    vbT[(size_t)(c0 + ty + i * 8) * 4096 + r0 + tx] = f2bf(tile[tx][ty + i * 8]);
}

// flash attention, 4-way key-split: grid 1024 = 16 qb x 16 h x 4 cls (LPT order).
// UNCHANGED from R6 best-known-good (86.5 us).
__global__ __launch_bounds__(256, 2) void attn(const short* __restrict__ qb,
                                               const short* __restrict__ kb,
                                               const short* __restrict__ vbT,
                                               short* __restrict__ Po,
                                               float* __restrict__ ml) {
  extern __shared__ __attribute__((aligned(16))) short smem[];
  short* Ks = smem;           // [2][64][128] shorts, swizzled
  short* Vs = smem + 16384;   // [2][128][64] shorts, swizzled
  const int tid = threadIdx.x, w = tid >> 6, l = tid & 63;
  const int g = l >> 4, lr = l & 15;
  const int lid = blockIdx.x;
  const int qbi = 15 - (lid >> 6);
  const int sub = lid & 63;
  const int h = sub >> 2, cls = sub & 3;
  const int kv = h >> 2;
  const int qw = qbi * 128 + w * 32;
  char* Pw = (char*)(smem + 32768) + w * 2048;
  const short* gK = kb + (size_t)kv * 4096 * 128;
  const short* gV = vbT + (size_t)kv * 128 * 4096;
  const int nT = 34 + 2 * qbi;
  const int cnt = (nT - cls + 3) >> 2;

  short8 aq[2][4];
#pragma unroll
  for (int u = 0; u < 2; ++u)
#pragma unroll
    for (int c4 = 0; c4 < 4; ++c4)
      aq[u][c4] = *(const short8*)(qb + ((size_t)(h * 2048 + qw + u * 16 + lr)) * 128 + c4 * 32 + g * 8);

  float m_r[2] = {-INFINITY, -INFINITY};
  float l_r[2] = {0.f, 0.f};
  f32x4 o[2][8] = {};

  auto stageK = [&](int buf, int s0) {
#pragma unroll
    for (int it = 0; it < 4; ++it) {
      int idx = it * 256 + tid;
      int row = idx >> 4;
      int colB = (idx & 15) * 16;
      int scol = colB ^ ((row & 7) << 4);
      gload_lds16(gK + (size_t)(s0 + row) * 128 + (scol >> 1),
                  Ks + buf * 8192 + (it * 256 + w * 64) * 8);
    }
  };
  auto stageV = [&](int buf, int s0) {
#pragma unroll
    for (int it = 0; it < 4; ++it) {
      int idx = it * 256 + tid;
      int row = idx >> 3;
      int colB = (idx & 7) * 16;
      int scol = colB ^ ((row & 7) << 4);
      gload_lds16(gV + (size_t)row * 4096 + s0 + (scol >> 1),
                  Vs + buf * 8192 + (it * 256 + w * 64) * 8);
    }
  };

  stageK(0, cls * 64);
  stageV(0, cls * 64);
  __syncthreads();
  int cur = 0;
  for (int i = 0; i < cnt; ++i) {
    const int s0 = (cls + 4 * i) * 64;
    if (i + 1 < cnt) {
      stageK(cur ^ 1, s0 + 256);
      stageV(cur ^ 1, s0 + 256);
    }
    f32x4 sc[2][4] = {};
    __builtin_amdgcn_s_setprio(1);
#pragma unroll
    for (int cc = 0; cc < 4; ++cc) {
      const int rb = cur * 8192 + (cc * 16 + lr) * 128;
      short8 bk[4];
#pragma unroll
      for (int c4 = 0; c4 < 4; ++c4)
        bk[c4] = *(const short8*)(Ks + rb + (((c4 * 64 + g * 16) ^ ((lr & 7) << 4)) >> 1));
#pragma unroll
      for (int c4 = 0; c4 < 4; ++c4) {
        sc[0][cc] = __builtin_amdgcn_mfma_f32_16x16x32_bf16(bk[c4], aq[0][c4], sc[0][cc], 0, 0, 0);
        sc[1][cc] = __builtin_amdgcn_mfma_f32_16x16x32_bf16(bk[c4], aq[1][c4], sc[1][cc], 0, 0, 0);
      }
    }
    __builtin_amdgcn_s_setprio(0);
    if (s0 + 63 > 2048 + qw) {
#pragma unroll
      for (int u = 0; u < 2; ++u)
#pragma unroll
        for (int cc = 0; cc < 4; ++cc)
#pragma unroll
          for (int r = 0; r < 4; ++r)
            sc[u][cc][r] = (s0 + cc * 16 + g * 4 + r <= 2048 + qw + u * 16 + lr)
                               ? sc[u][cc][r] : -INFINITY;
    }
    short8 ap[2][2];
#pragma unroll
    for (int u = 0; u < 2; ++u) {
      float pmax = -INFINITY;
#pragma unroll
      for (int cc = 0; cc < 4; ++cc) {
        float a = fmaxf(fmaxf(sc[u][cc][0], sc[u][cc][1]), fmaxf(sc[u][cc][2], sc[u][cc][3]));
        pmax = fmaxf(pmax, a);
      }
      if (!__all(pmax - m_r[u] <= 8.0f)) {
        float tm = fmaxf(pmax, __shfl_xor(pmax, 16, 64));
        tm = fmaxf(tm, __shfl_xor(tm, 32, 64));
        float mn = fmaxf(m_r[u], tm);
        float corr = exp2f(m_r[u] - mn);
        m_r[u] = mn;
        l_r[u] *= corr;
        float co[4];
#pragma unroll
        for (int r = 0; r < 4; ++r) co[r] = __shfl(corr, (l & 48) | (g * 4 + r), 64);
#pragma unroll
        for (int d8 = 0; d8 < 8; ++d8) {
          f32x4 tt = o[u][d8];
#pragma unroll
          for (int r = 0; r < 4; ++r) tt[r] *= co[r];
          o[u][d8] = tt;
        }
      }
      float ps = 0.f;
#pragma unroll
      for (int cc = 0; cc < 4; ++cc) {
        float p0 = exp2f(sc[u][cc][0] - m_r[u]);
        float p1 = exp2f(sc[u][cc][1] - m_r[u]);
        float p2 = exp2f(sc[u][cc][2] - m_r[u]);
        float p3 = exp2f(sc[u][cc][3] - m_r[u]);
        ps += (p0 + p1) + (p2 + p3);
        unsigned pk0 = cvt_pk_bf16(p0, p1);
        unsigned pk1 = cvt_pk_bf16(p2, p3);
        int off8 = (lr * 128 + cc * 32 + g * 8) ^ ((lr & 7) << 4);
        unsigned long long pq = (unsigned long long)pk0 | ((unsigned long long)pk1 << 32);
        *(unsigned long long*)(Pw + off8) = pq;
      }
      l_r[u] += ps;
#pragma unroll
      for (int ks = 0; ks < 2; ++ks)
        ap[u][ks] = *(const short8*)(Pw + ((lr * 128 + ks * 64 + g * 16) ^ ((lr & 7) << 4)));
    }
    __builtin_amdgcn_s_setprio(1);
#pragma unroll
    for (int d8 = 0; d8 < 8; ++d8) {
      const int rb = cur * 8192 + (d8 * 16 + lr) * 64;
      short8 bv0 = *(const short8*)(Vs + rb + (((0 * 64 + g * 16) ^ ((lr & 7) << 4)) >> 1));
      short8 bv1 = *(const short8*)(Vs + rb + (((1 * 64 + g * 16) ^ ((lr & 7) << 4)) >> 1));
      o[0][d8] = __builtin_amdgcn_mfma_f32_16x16x32_bf16(ap[0][0], bv0, o[0][d8], 0, 0, 0);
      o[0][d8] = __builtin_amdgcn_mfma_f32_16x16x32_bf16(ap[0][1], bv1, o[0][d8], 0, 0, 0);
      o[1][d8] = __builtin_amdgcn_mfma_f32_16x16x32_bf16(ap[1][0], bv0, o[1][d8], 0, 0, 0);
      o[1][d8] = __builtin_amdgcn_mfma_f32_16x16x32_bf16(ap[1][1], bv1, o[1][d8], 0, 0, 0);
    }
    __builtin_amdgcn_s_setprio(0);
    __syncthreads();
    cur ^= 1;
  }
#pragma unroll
  for (int u = 0; u < 2; ++u) {
    float ls = l_r[u];
    ls += __shfl_xor(ls, 16, 64);
    ls += __shfl_xor(ls, 32, 64);
    float inv = 1.0f / ls;
    float invo[4];
#pragma unroll
    for (int r = 0; r < 4; ++r) invo[r] = __shfl(inv, (l & 48) | (g * 4 + r), 64);
#pragma unroll
    for (int d8 = 0; d8 < 8; ++d8)
#pragma unroll
      for (int r = 0; r < 4; ++r)
        Po[((size_t)(cls * 16 + h) * 2048 + qw + u * 16 + g * 4 + r) * 128 + d8 * 16 + lr] =
            f2h(o[u][d8][r] * invo[r]);
    if (g == 0) {
      float2 v;
      v.x = m_r[u];
      v.y = ls;
      ((float2*)ml)[(size_t)(cls * 16 + h) * 2048 + qw + u * 16 + lr] = v;
    }
  }
}

// merge 4 key-split partials -> ya (bf16). one thread per (q, h, 8-d chunk).
__global__ __launch_bounds__(256) void attn_merge(const short* __restrict__ Po,
                                                  const float* __restrict__ ml,
                                                  short* __restrict__ ya) {
  int i = blockIdx.x * 256 + threadIdx.x;  // 0..524287
  int q = i >> 8, rem = i & 255, h = rem >> 4, oct = rem & 15;
  float mc[4], lc[4], m = -INFINITY;
#pragma unroll
  for (int c = 0; c < 4; ++c) {
    float2 v = ((const float2*)ml)[(size_t)(c * 16 + h) * 2048 + q];
    mc[c] = v.x; lc[c] = v.y;
    m = fmaxf(m, mc[c]);
  }
  float wsum = 0.f, acc[8] = {};
#pragma unroll
  for (int c = 0; c < 4; ++c) {
    float wc = lc[c] * exp2f(mc[c] - m);
    wsum += wc;
    short8 p = *(const short8*)(Po + ((size_t)(c * 16 + h) * 2048 + q) * 128 + oct * 8);
#pragma unroll
    for (int j = 0; j < 8; ++j) acc[j] += wc * h2f(p[j]);
  }
  float inv = 1.0f / wsum;
  short8 ov;
#pragma unroll
  for (int j = 0; j < 8; ++j) ov[j] = f2bf(acc[j] * inv);
  *(short8*)(ya + (size_t)q * 2048 + h * 128 + oct * 8) = ov;
}

extern "C" void kernel_launch(void* const* d_in, const int* in_sizes, int n_in,
                              void* d_out, int out_size, void* d_ws, size_t ws_size,
                              hipStream_t stream) {
  const float* x = (const float*)d_in[0];
  const float* ve = (const float*)d_in[1];
  const float* cosb = (const float*)d_in[2];
  const float* sinb = (const float*)d_in[3];
  const float* past_key = (const float*)d_in[4];
  const float* past_value = (const float*)d_in[5];
  const float* Wq = (const float*)d_in[6];
  const float* Wk = (const float*)d_in[7];
  const float* Wv = (const float*)d_in[8];
  const float* Wo = (const float*)d_in[9];
  const float* Wg = (const float*)d_in[10];

  float* outY = (float*)d_out;          // 2048*2048
  float* outPK = outY + 4194304;        // 4096*4*128
  float* outPV = outPK + 2097152;       // 4096*4*128

  short* base = (short*)d_ws;
  short* WToT = base;                               // 2048*2048 bf16 (live to the end)
  short* WTqkv = base + 4194304;                    // 3072*2048 bf16  (dead after gemm1)
  short* xb = WTqkv + (size_t)6291456;              // 2048*2048 bf16  (dead after gemm1)
  float* qkv = (float*)(xb + (size_t)4194304);      // 2048*3072 f32   (dead after qkv_post)
  short* qb = (short*)(qkv + (size_t)6291456);      // 16*2048*128 bf16
  short* kb = qb + (size_t)4194304;                 // 4*4096*128 bf16
  short* vbT = kb + (size_t)2097152;                // 4*128*4096 bf16 (transposed)
  short* ya = vbT + (size_t)2097152;                // 2048*2048 bf16
  // attn partials alias the dead WTqkv/xb/qkv pool:
  short* Po = WTqkv;                                // 4*16*2048*128 f16 = 16777216 shorts
  float* mlb = (float*)(base + 20971520);           // 4*16*2048 float2 = 1048576 floats

  static bool attr_set = false;
  if (!attr_set) {
    (void)hipFuncSetAttribute((const void*)attn,
                              hipFuncAttributeMaxDynamicSharedMemorySize, 73728);
    attr_set = true;
  }

  cvt_x<<<4096, 256, 0, stream>>>(x, xb, 1048576);
  transpose_all<<<dim3(160, 64), dim3(32, 8), 0, stream>>>(Wq, Wk, Wv, Wo, WTqkv, WToT);

  gemm_bf16<<<dim3(24, 16), 256, 0, stream>>>(xb, WTqkv, qkv, 2048, 3072, 2048);

  qkv_post<<<12288, 256, 0, stream>>>(qkv, cosb, sinb, x, ve, Wg, outPK, outPV, qb, kb);
  past_copy<<<4096, 256, 0, stream>>>(past_key, past_value, outPK, outPV, kb);
  v_transpose<<<dim3(16, 128), dim3(32, 8), 0, stream>>>(outPV, vbT);

  attn<<<1024, 256, 73728, stream>>>(qb, kb, vbT, Po, mlb);
  attn_merge<<<2048, 256, 0, stream>>>(Po, mlb, ya);

  gemm_bf16_k64<<<dim3(16, 16), 256, 0, stream>>>(ya, WToT, outY, 2048, 2048, 2048);
}

// Round 8
// 185.328 us; speedup vs baseline: 1.8645x; 1.0226x over previous
//
#include <hip/hip_runtime.h>
#include <hip/hip_bf16.h>
#include <math.h>

typedef __attribute__((ext_vector_type(8))) short short8;
typedef __attribute__((ext_vector_type(4))) short short4v;
typedef __attribute__((ext_vector_type(4))) float f32x4;

#define DEV __device__ __forceinline__

DEV short f2bf(float f) {
  unsigned u = __builtin_bit_cast(unsigned, f);
  unsigned r = (u + 0x7FFFu + ((u >> 16) & 1u)) >> 16;
  return (short)r;
}

DEV short f2h(float f) {
  _Float16 h = (_Float16)f;
  return __builtin_bit_cast(short, h);
}

DEV float h2f(short s) {
  return (float)__builtin_bit_cast(_Float16, s);
}

DEV unsigned cvt_pk_bf16(float lo, float hi) {
  unsigned r;
  asm("v_cvt_pk_bf16_f32 %0, %1, %2" : "=v"(r) : "v"(lo), "v"(hi));
  return r;
}

DEV void gload_lds16(const void* g, void* l) {
  __builtin_amdgcn_global_load_lds((const __attribute__((address_space(1))) void*)g,
                                   (__attribute__((address_space(3))) void*)l, 16, 0, 0);
}

// C[M x N] (f32) = A[M x K] (bf16) * BT[N x K]^T, BK=32, 2-phase dbuf + XCD swizzle.
__global__ __launch_bounds__(256) void gemm_bf16(const short* __restrict__ A,
                                                 const short* __restrict__ BT,
                                                 float* __restrict__ C,
                                                 int M, int N, int K) {
  __shared__ __attribute__((aligned(16))) short As[2][128 * 32];
  __shared__ __attribute__((aligned(16))) short Bs[2][128 * 32];
  const int tid = threadIdx.x;
  const int w = tid >> 6, l = tid & 63;
  const int g = l >> 4, lr = l & 15;
  int nbx = gridDim.x, nwg = nbx * gridDim.y;
  int flat = blockIdx.y * nbx + blockIdx.x;
  int qq = nwg >> 3;
  int f2 = (flat & 7) * qq + (flat >> 3);
  const int m0 = (f2 / nbx) * 128, n0 = (f2 % nbx) * 128;
  const int wr = w >> 1, wc = w & 1;
  const int q0 = w * 2, q1 = w * 2 + 1;
  const int e0 = q0 * 512 + l * 8, e1 = q1 * 512 + l * 8;
  const int ra = e0 >> 5, ka = e0 & 31;
  const int rb_ = e1 >> 5, kb_ = e1 & 31;
  f32x4 acc[4][4] = {};

  auto stage = [&](int buf, int k0) {
    gload_lds16(A + (size_t)(m0 + ra) * K + k0 + ka, As[buf] + q0 * 512);
    gload_lds16(BT + (size_t)(n0 + ra) * K + k0 + ka, Bs[buf] + q0 * 512);
    gload_lds16(A + (size_t)(m0 + rb_) * K + k0 + kb_, As[buf] + q1 * 512);
    gload_lds16(BT + (size_t)(n0 + rb_) * K + k0 + kb_, Bs[buf] + q1 * 512);
  };

  stage(0, 0);
  __syncthreads();
  int cur = 0;
  for (int k0 = 0; k0 < K; k0 += 32) {
    if (k0 + 32 < K) stage(cur ^ 1, k0 + 32);
    short8 af[4], bfr[4];
#pragma unroll
    for (int i = 0; i < 4; ++i) {
      af[i] = *(const short8*)(As[cur] + (wr * 64 + i * 16 + lr) * 32 + g * 8);
      bfr[i] = *(const short8*)(Bs[cur] + (wc * 64 + i * 16 + lr) * 32 + g * 8);
    }
#pragma unroll
    for (int mi = 0; mi < 4; ++mi)
#pragma unroll
      for (int ni = 0; ni < 4; ++ni)
        acc[mi][ni] = __builtin_amdgcn_mfma_f32_16x16x32_bf16(af[mi], bfr[ni], acc[mi][ni], 0, 0, 0);
    __syncthreads();
    cur ^= 1;
  }
#pragma unroll
  for (int mi = 0; mi < 4; ++mi)
#pragma unroll
    for (int ni = 0; ni < 4; ++ni) {
      int row = m0 + wr * 64 + mi * 16 + g * 4;
      int col = n0 + wc * 64 + ni * 16 + lr;
#pragma unroll
      for (int r = 0; r < 4; ++r)
        C[(size_t)(row + r) * N + col] = acc[mi][ni][r];
    }
}

// BK=64 variant for the 1-block/CU regime (gemm2).
__global__ __launch_bounds__(256) void gemm_bf16_k64(const short* __restrict__ A,
                                                     const short* __restrict__ BT,
                                                     float* __restrict__ C,
                                                     int M, int N, int K) {
  __shared__ __attribute__((aligned(16))) short As[2][128 * 64];
  __shared__ __attribute__((aligned(16))) short Bs[2][128 * 64];
  const int tid = threadIdx.x;
  const int w = tid >> 6, l = tid & 63;
  const int g = l >> 4, lr = l & 15;
  int nbx = gridDim.x, nwg = nbx * gridDim.y;
  int flat = blockIdx.y * nbx + blockIdx.x;
  int qq = nwg >> 3;
  int f2 = (flat & 7) * qq + (flat >> 3);
  const int m0 = (f2 / nbx) * 128, n0 = (f2 % nbx) * 128;
  const int wr = w >> 1, wc = w & 1;
  f32x4 acc[4][4] = {};

  auto stage = [&](int buf, int k0) {
#pragma unroll
    for (int it = 0; it < 4; ++it) {
      int idx = it * 256 + tid;
      int row = idx >> 3;
      int colB = (idx & 7) * 16;
      int scol = colB ^ ((row & 7) << 4);
      gload_lds16(A + (size_t)(m0 + row) * K + k0 + (scol >> 1), As[buf] + idx * 8);
      gload_lds16(BT + (size_t)(n0 + row) * K + k0 + (scol >> 1), Bs[buf] + idx * 8);
    }
  };

  stage(0, 0);
  __syncthreads();
  int cur = 0;
  for (int k0 = 0; k0 < K; k0 += 64) {
    if (k0 + 64 < K) stage(cur ^ 1, k0 + 64);
#pragma unroll
    for (int ki = 0; ki < 2; ++ki) {
      short8 af[4], bfr[4];
#pragma unroll
      for (int i = 0; i < 4; ++i) {
        int off = ((wr * 64 + i * 16 + lr) * 128 + ((ki * 64 + g * 16) ^ ((lr & 7) << 4))) >> 1;
        int offb = ((wc * 64 + i * 16 + lr) * 128 + ((ki * 64 + g * 16) ^ ((lr & 7) << 4))) >> 1;
        af[i] = *(const short8*)(As[cur] + off);
        bfr[i] = *(const short8*)(Bs[cur] + offb);
      }
#pragma unroll
      for (int mi = 0; mi < 4; ++mi)
#pragma unroll
        for (int ni = 0; ni < 4; ++ni)
          acc[mi][ni] = __builtin_amdgcn_mfma_f32_16x16x32_bf16(af[mi], bfr[ni], acc[mi][ni], 0, 0, 0);
    }
    __syncthreads();
    cur ^= 1;
  }
#pragma unroll
  for (int mi = 0; mi < 4; ++mi)
#pragma unroll
    for (int ni = 0; ni < 4; ++ni) {
      int row = m0 + wr * 64 + mi * 16 + g * 4;
      int col = n0 + wc * 64 + ni * 16 + lr;
#pragma unroll
      for (int r = 0; r < 4; ++r)
        C[(size_t)(row + r) * N + col] = acc[mi][ni][r];
    }
}

// Fused prep: bid<4096 -> cvt_x; else the 4 weight transposes (flattened 160x64).
__global__ __launch_bounds__(256) void prep(const float* __restrict__ x,
                                            short* __restrict__ xb,
                                            const float* __restrict__ Wq,
                                            const float* __restrict__ Wk,
                                            const float* __restrict__ Wv,
                                            const float* __restrict__ Wo,
                                            short* __restrict__ WTqkv,
                                            short* __restrict__ WToT) {
  __shared__ float tile[32][33];
  int bid = blockIdx.x;
  int tid = threadIdx.x;
  if (bid < 4096) {
    int i = bid * 256 + tid;
    float4 v = ((const float4*)x)[i];
    short4v o;
    o.x = f2bf(v.x); o.y = f2bf(v.y); o.z = f2bf(v.z); o.w = f2bf(v.w);
    ((short4v*)xb)[i] = o;
    return;
  }
  int b = bid - 4096;
  int bx = b % 160, by = b / 160;
  const float* W;
  short* WT;
  int N, cb;
  if (bx < 64) { W = Wq; WT = WTqkv; N = 2048; cb = bx; }
  else if (bx < 80) { W = Wk; WT = WTqkv + (size_t)2048 * 2048; N = 512; cb = bx - 64; }
  else if (bx < 96) { W = Wv; WT = WTqkv + (size_t)2560 * 2048; N = 512; cb = bx - 80; }
  else { W = Wo; WT = WToT; N = 2048; cb = bx - 96; }
  int tx = tid & 31, ty = tid >> 5;
  int c0 = cb * 32, r0 = by * 32;
#pragma unroll
  for (int i = 0; i < 4; ++i)
    tile[ty + i * 8][tx] = W[(size_t)(r0 + ty + i * 8) * N + c0 + tx];
  __syncthreads();
#pragma unroll
  for (int i = 0; i < 4; ++i)
    WT[(size_t)(c0 + ty + i * 8) * 2048 + r0 + tx] = f2bf(tile[tx][ty + i * 8]);
}

// Fused qk_post + v_gate: one wave per (t, u), u in [0,24).
__global__ __launch_bounds__(256) void qkv_post(const float* __restrict__ qkv,
                                                const float* __restrict__ cosb,
                                                const float* __restrict__ sinb,
                                                const float* __restrict__ x,
                                                const float* __restrict__ ve,
                                                const float* __restrict__ Wg,
                                                float* __restrict__ outPK,
                                                float* __restrict__ outPV,
                                                short* __restrict__ qb,
                                                short* __restrict__ kb) {
  int gw = (blockIdx.x * 256 + threadIdx.x) >> 6;
  int l = threadIdx.x & 63;
  int t = gw / 24, u = gw - t * 24;
  if (t >= 2048) return;
  if (u < 20) {
    float c = cosb[t * 64 + l], s = sinb[t * 64 + l];
    const float* src = qkv + (size_t)t * 3072 + (u < 16 ? u * 128 : 2048 + (u - 16) * 128);
    float x1 = src[l], x2 = src[64 + l];
    float lo = x1 * c + x2 * s;
    float hi = x2 * c - x1 * s;
    float ss = lo * lo + hi * hi;
#pragma unroll
    for (int d = 1; d < 64; d <<= 1) ss += __shfl_xor(ss, d, 64);
    float r = rsqrtf(ss * (1.0f / 128.0f) + 1e-6f) * 1.2f;
    if (u < 16) {
      const float SCQ = 0.08838834764831845f * 1.4426950408889634f;
      float rq = r * SCQ;
      size_t b = ((size_t)u * 2048 + t) * 128;
      qb[b + l] = f2bf(lo * rq);
      qb[b + 64 + l] = f2bf(hi * rq);
    } else {
      lo *= r; hi *= r;
      int kvh = u - 16;
      size_t b = ((size_t)(2048 + t) * 4 + kvh) * 128;
      outPK[b + l] = lo;
      outPK[b + 64 + l] = hi;
      size_t b2 = ((size_t)kvh * 4096 + 2048 + t) * 128;
      kb[b2 + l] = f2bf(lo);
      kb[b2 + 64 + l] = f2bf(hi);
    }
  } else {
    int kv = u - 20;
    float z = 0.f;
#pragma unroll
    for (int j = 0; j < 12; ++j) z += x[(size_t)t * 2048 + j] * Wg[j * 4 + kv];
    float gate = 3.0f / (1.0f + expf(-z));
    const float* vr = qkv + (size_t)t * 3072 + 2560 + kv * 128;
    const float* vei = ve + (size_t)t * 512 + kv * 128;
    float v0 = vr[l] + gate * vei[l];
    float v1 = vr[64 + l] + gate * vei[64 + l];
    size_t b = ((size_t)(2048 + t) * 4 + kv) * 128;
    outPV[b + l] = v0;
    outPV[b + 64 + l] = v1;
  }
}

__global__ __launch_bounds__(256) void past_copy(const float* __restrict__ pk,
                                                 const float* __restrict__ pv,
                                                 float* __restrict__ outPK,
                                                 float* __restrict__ outPV,
                                                 short* __restrict__ kb) {
  int i = blockIdx.x * 256 + threadIdx.x;  // 0..1048575
  int d = i & 127, kv = (i >> 7) & 3, s = i >> 9;
  float a = pk[i], b = pv[i];
  outPK[i] = a;
  outPV[i] = b;
  kb[((size_t)kv * 4096 + s) * 128 + d] = f2bf(a);
}

// vbT transpose: LDS-tiled, coalesced both sides. grid (16, 128), block 256 flat.
__global__ __launch_bounds__(256) void v_transpose(const float* __restrict__ PV,
                                                   short* __restrict__ vbT) {
  __shared__ float tile[32][33];
  int tx = threadIdx.x & 31, ty = threadIdx.x >> 5;
  int c0 = blockIdx.x * 32, r0 = blockIdx.y * 32;
#pragma unroll
  for (int i = 0; i < 4; ++i)
    tile[ty + i * 8][tx] = PV[(size_t)(r0 + ty + i * 8) * 512 + c0 + tx];
  __syncthreads();
#pragma unroll
  for (int i = 0; i < 4; ++i)
    vbT[(size_t)(c0 + ty + i * 8) * 4096 + r0 + tx] = f2bf(tile[tx][ty + i * 8]);
}

// flash attention, 2-way key-split: grid 512; rank r = lid>>5 (heavy-first LPT),
// sub = lid&31: h = sub>>1, cls = sub&1. cnt = 32-r for BOTH classes -> FIFO
// backfill pairs always sum to 49 iters/CU. Running-pointer staging (constant
// stride advance). Otherwise identical to the proven R6 structure.
__global__ __launch_bounds__(256, 2) void attn(const short* __restrict__ qb,
                                               const short* __restrict__ kb,
                                               const short* __restrict__ vbT,
                                               short* __restrict__ Po,
                                               float* __restrict__ ml) {
  extern __shared__ __attribute__((aligned(16))) short smem[];
  short* Ks = smem;           // [2][64][128] shorts, swizzled
  short* Vs = smem + 16384;   // [2][128][64] shorts, swizzled
  const int tid = threadIdx.x, w = tid >> 6, l = tid & 63;
  const int g = l >> 4, lr = l & 15;
  const int lid = blockIdx.x;
  const int qbi = 15 - (lid >> 5);
  const int sub = lid & 31;
  const int h = sub >> 1, cls = sub & 1;
  const int kv = h >> 2;
  const int qw = qbi * 128 + w * 32;
  char* Pw = (char*)(smem + 32768) + w * 2048;
  const short* gK = kb + (size_t)kv * 4096 * 128;
  const short* gV = vbT + (size_t)kv * 128 * 4096;
  const int nT = 34 + 2 * qbi;
  const int cnt = (nT - cls + 1) >> 1;

  short8 aq[2][4];
#pragma unroll
  for (int u = 0; u < 2; ++u)
#pragma unroll
    for (int c4 = 0; c4 < 4; ++c4)
      aq[u][c4] = *(const short8*)(qb + ((size_t)(h * 2048 + qw + u * 16 + lr)) * 128 + c4 * 32 + g * 8);

  float m_r[2] = {-INFINITY, -INFINITY};
  float l_r[2] = {0.f, 0.f};
  f32x4 o[2][8] = {};

  // running-pointer staging (source swizzle pre-applied; strides are constants)
  const int rK = tid >> 4, cKs = ((tid & 15) * 16) ^ ((rK & 7) << 4);
  const int rV = tid >> 3, cVs = ((tid & 7) * 16) ^ ((rV & 7) << 4);
  const short* kptr = gK + (size_t)(cls * 64 + rK) * 128 + (cKs >> 1);
  const short* vptr = gV + (size_t)rV * 4096 + cls * 64 + (cVs >> 1);
  short* kdst = Ks + w * 512;
  short* vdst = Vs + w * 512;

  auto stageK = [&](int buf) {
#pragma unroll
    for (int it = 0; it < 4; ++it)
      gload_lds16(kptr + it * 2048, kdst + buf * 8192 + it * 2048);
    kptr += 16384;  // next staged tile: +128 keys * 128 d shorts
  };
  auto stageV = [&](int buf) {
#pragma unroll
    for (int it = 0; it < 4; ++it)
      gload_lds16(vptr + (size_t)it * 131072, vdst + buf * 8192 + it * 2048);
    vptr += 128;    // next staged tile: +128 keys along the s axis
  };

  stageK(0);
  stageV(0);
  __syncthreads();
  int cur = 0;
  for (int i = 0; i < cnt; ++i) {
    const int s0 = (cls + 2 * i) * 64;
    if (i + 1 < cnt) {
      stageK(cur ^ 1);
      stageV(cur ^ 1);
    }
    f32x4 sc[2][4] = {};
    __builtin_amdgcn_s_setprio(1);
#pragma unroll
    for (int cc = 0; cc < 4; ++cc) {
      const int rb = cur * 8192 + (cc * 16 + lr) * 128;
      short8 bk[4];
#pragma unroll
      for (int c4 = 0; c4 < 4; ++c4)
        bk[c4] = *(const short8*)(Ks + rb + (((c4 * 64 + g * 16) ^ ((lr & 7) << 4)) >> 1));
#pragma unroll
      for (int c4 = 0; c4 < 4; ++c4) {
        sc[0][cc] = __builtin_amdgcn_mfma_f32_16x16x32_bf16(bk[c4], aq[0][c4], sc[0][cc], 0, 0, 0);
        sc[1][cc] = __builtin_amdgcn_mfma_f32_16x16x32_bf16(bk[c4], aq[1][c4], sc[1][cc], 0, 0, 0);
      }
    }
    __builtin_amdgcn_s_setprio(0);
    if (s0 + 63 > 2048 + qw) {
#pragma unroll
      for (int u = 0; u < 2; ++u)
#pragma unroll
        for (int cc = 0; cc < 4; ++cc)
#pragma unroll
          for (int r = 0; r < 4; ++r)
            sc[u][cc][r] = (s0 + cc * 16 + g * 4 + r <= 2048 + qw + u * 16 + lr)
                               ? sc[u][cc][r] : -INFINITY;
    }
    short8 ap[2][2];
#pragma unroll
    for (int u = 0; u < 2; ++u) {
      float pmax = -INFINITY;
#pragma unroll
      for (int cc = 0; cc < 4; ++cc) {
        float a = fmaxf(fmaxf(sc[u][cc][0], sc[u][cc][1]), fmaxf(sc[u][cc][2], sc[u][cc][3]));
        pmax = fmaxf(pmax, a);
      }
      if (!__all(pmax - m_r[u] <= 8.0f)) {
        float tm = fmaxf(pmax, __shfl_xor(pmax, 16, 64));
        tm = fmaxf(tm, __shfl_xor(tm, 32, 64));
        float mn = fmaxf(m_r[u], tm);
        float corr = exp2f(m_r[u] - mn);
        m_r[u] = mn;
        l_r[u] *= corr;
        float co[4];
#pragma unroll
        for (int r = 0; r < 4; ++r) co[r] = __shfl(corr, (l & 48) | (g * 4 + r), 64);
#pragma unroll
        for (int d8 = 0; d8 < 8; ++d8) {
          f32x4 tt = o[u][d8];
#pragma unroll
          for (int r = 0; r < 4; ++r) tt[r] *= co[r];
          o[u][d8] = tt;
        }
      }
      float ps = 0.f;
#pragma unroll
      for (int cc = 0; cc < 4; ++cc) {
        float p0 = exp2f(sc[u][cc][0] - m_r[u]);
        float p1 = exp2f(sc[u][cc][1] - m_r[u]);
        float p2 = exp2f(sc[u][cc][2] - m_r[u]);
        float p3 = exp2f(sc[u][cc][3] - m_r[u]);
        ps += (p0 + p1) + (p2 + p3);
        unsigned pk0 = cvt_pk_bf16(p0, p1);
        unsigned pk1 = cvt_pk_bf16(p2, p3);
        int off8 = (lr * 128 + cc * 32 + g * 8) ^ ((lr & 7) << 4);
        unsigned long long pq = (unsigned long long)pk0 | ((unsigned long long)pk1 << 32);
        *(unsigned long long*)(Pw + off8) = pq;
      }
      l_r[u] += ps;
#pragma unroll
      for (int ks = 0; ks < 2; ++ks)
        ap[u][ks] = *(const short8*)(Pw + ((lr * 128 + ks * 64 + g * 16) ^ ((lr & 7) << 4)));
    }
    __builtin_amdgcn_s_setprio(1);
#pragma unroll
    for (int d8 = 0; d8 < 8; ++d8) {
      const int rb = cur * 8192 + (d8 * 16 + lr) * 64;
      short8 bv0 = *(const short8*)(Vs + rb + (((0 * 64 + g * 16) ^ ((lr & 7) << 4)) >> 1));
      short8 bv1 = *(const short8*)(Vs + rb + (((1 * 64 + g * 16) ^ ((lr & 7) << 4)) >> 1));
      o[0][d8] = __builtin_amdgcn_mfma_f32_16x16x32_bf16(ap[0][0], bv0, o[0][d8], 0, 0, 0);
      o[0][d8] = __builtin_amdgcn_mfma_f32_16x16x32_bf16(ap[0][1], bv1, o[0][d8], 0, 0, 0);
      o[1][d8] = __builtin_amdgcn_mfma_f32_16x16x32_bf16(ap[1][0], bv0, o[1][d8], 0, 0, 0);
      o[1][d8] = __builtin_amdgcn_mfma_f32_16x16x32_bf16(ap[1][1], bv1, o[1][d8], 0, 0, 0);
    }
    __builtin_amdgcn_s_setprio(0);
    __syncthreads();
    cur ^= 1;
  }
#pragma unroll
  for (int u = 0; u < 2; ++u) {
    float ls = l_r[u];
    ls += __shfl_xor(ls, 16, 64);
    ls += __shfl_xor(ls, 32, 64);
    float inv = 1.0f / ls;
    float invo[4];
#pragma unroll
    for (int r = 0; r < 4; ++r) invo[r] = __shfl(inv, (l & 48) | (g * 4 + r), 64);
#pragma unroll
    for (int d8 = 0; d8 < 8; ++d8)
#pragma unroll
      for (int r = 0; r < 4; ++r)
        Po[((size_t)(cls * 16 + h) * 2048 + qw + u * 16 + g * 4 + r) * 128 + d8 * 16 + lr] =
            f2h(o[u][d8][r] * invo[r]);
    if (g == 0) {
      float2 v;
      v.x = m_r[u];
      v.y = ls;
      ((float2*)ml)[(size_t)(cls * 16 + h) * 2048 + qw + u * 16 + lr] = v;
    }
  }
}

// merge 2 key-split partials -> ya (bf16). one thread per (q, h, 8-d chunk).
__global__ __launch_bounds__(256) void attn_merge(const short* __restrict__ Po,
                                                  const float* __restrict__ ml,
                                                  short* __restrict__ ya) {
  int i = blockIdx.x * 256 + threadIdx.x;  // 0..524287
  int q = i >> 8, rem = i & 255, h = rem >> 4, oct = rem & 15;
  float mc[2], lc[2];
#pragma unroll
  for (int c = 0; c < 2; ++c) {
    float2 v = ((const float2*)ml)[(size_t)(c * 16 + h) * 2048 + q];
    mc[c] = v.x; lc[c] = v.y;
  }
  float m = fmaxf(mc[0], mc[1]);
  float wsum = 0.f, acc[8] = {};
#pragma unroll
  for (int c = 0; c < 2; ++c) {
    float wc = lc[c] * exp2f(mc[c] - m);
    wsum += wc;
    short8 p = *(const short8*)(Po + ((size_t)(c * 16 + h) * 2048 + q) * 128 + oct * 8);
#pragma unroll
    for (int j = 0; j < 8; ++j) acc[j] += wc * h2f(p[j]);
  }
  float inv = 1.0f / wsum;
  short8 ov;
#pragma unroll
  for (int j = 0; j < 8; ++j) ov[j] = f2bf(acc[j] * inv);
  *(short8*)(ya + (size_t)q * 2048 + h * 128 + oct * 8) = ov;
}

extern "C" void kernel_launch(void* const* d_in, const int* in_sizes, int n_in,
                              void* d_out, int out_size, void* d_ws, size_t ws_size,
                              hipStream_t stream) {
  const float* x = (const float*)d_in[0];
  const float* ve = (const float*)d_in[1];
  const float* cosb = (const float*)d_in[2];
  const float* sinb = (const float*)d_in[3];
  const float* past_key = (const float*)d_in[4];
  const float* past_value = (const float*)d_in[5];
  const float* Wq = (const float*)d_in[6];
  const float* Wk = (const float*)d_in[7];
  const float* Wv = (const float*)d_in[8];
  const float* Wo = (const float*)d_in[9];
  const float* Wg = (const float*)d_in[10];

  float* outY = (float*)d_out;          // 2048*2048
  float* outPK = outY + 4194304;        // 4096*4*128
  float* outPV = outPK + 2097152;       // 4096*4*128

  short* base = (short*)d_ws;
  short* WToT = base;                               // 2048*2048 bf16 (live to the end)
  short* WTqkv = base + 4194304;                    // 3072*2048 bf16  (dead after gemm1)
  short* xb = WTqkv + (size_t)6291456;              // 2048*2048 bf16  (dead after gemm1)
  float* qkv = (float*)(xb + (size_t)4194304);      // 2048*3072 f32   (dead after qkv_post)
  short* qb = (short*)(qkv + (size_t)6291456);      // 16*2048*128 bf16
  short* kb = qb + (size_t)4194304;                 // 4*4096*128 bf16
  short* vbT = kb + (size_t)2097152;                // 4*128*4096 bf16 (transposed)
  short* ya = vbT + (size_t)2097152;                // 2048*2048 bf16
  // attn partials alias the dead WTqkv/xb/qkv pool:
  short* Po = WTqkv;                                // 2*16*2048*128 f16 = 8388608 shorts
  float* mlb = (float*)(base + 20971520);           // 2*16*2048 float2 = 524288 floats

  static bool attr_set = false;
  if (!attr_set) {
    (void)hipFuncSetAttribute((const void*)attn,
                              hipFuncAttributeMaxDynamicSharedMemorySize, 73728);
    attr_set = true;
  }

  prep<<<14336, 256, 0, stream>>>(x, xb, Wq, Wk, Wv, Wo, WTqkv, WToT);

  gemm_bf16<<<dim3(24, 16), 256, 0, stream>>>(xb, WTqkv, qkv, 2048, 3072, 2048);

  qkv_post<<<12288, 256, 0, stream>>>(qkv, cosb, sinb, x, ve, Wg, outPK, outPV, qb, kb);
  past_copy<<<4096, 256, 0, stream>>>(past_key, past_value, outPK, outPV, kb);
  v_transpose<<<dim3(16, 128), 256, 0, stream>>>(outPV, vbT);

  attn<<<512, 256, 73728, stream>>>(qb, kb, vbT, Po, mlb);
  attn_merge<<<2048, 256, 0, stream>>>(Po, mlb, ya);

  gemm_bf16_k64<<<dim3(16, 16), 256, 0, stream>>>(ya, WToT, outY, 2048, 2048, 2048);
}

// Round 9
// 181.402 us; speedup vs baseline: 1.9048x; 1.0216x over previous
//
#include <hip/hip_runtime.h>
#include <hip/hip_bf16.h>
#include <math.h>

typedef __attribute__((ext_vector_type(8))) short short8;
typedef __attribute__((ext_vector_type(4))) short short4v;
typedef __attribute__((ext_vector_type(4))) float f32x4;

#define DEV __device__ __forceinline__

DEV short f2bf(float f) {
  unsigned u = __builtin_bit_cast(unsigned, f);
  unsigned r = (u + 0x7FFFu + ((u >> 16) & 1u)) >> 16;
  return (short)r;
}

DEV short f2h(float f) {
  _Float16 h = (_Float16)f;
  return __builtin_bit_cast(short, h);
}

DEV float h2f(short s) {
  return (float)__builtin_bit_cast(_Float16, s);
}

DEV unsigned cvt_pk_bf16(float lo, float hi) {
  unsigned r;
  asm("v_cvt_pk_bf16_f32 %0, %1, %2" : "=v"(r) : "v"(lo), "v"(hi));
  return r;
}

DEV void gload_lds16(const void* g, void* l) {
  __builtin_amdgcn_global_load_lds((const __attribute__((address_space(1))) void*)g,
                                   (__attribute__((address_space(3))) void*)l, 16, 0, 0);
}

// gemm1: C[M x N] f32 = A[M x K] bf16 * BT[N x K]^T. BM=64, BN=128, BK=64.
// grid 24x32 = 768 blocks = 3/CU balanced; 48KB LDS; XOR-swizzle; 2-phase dbuf.
__global__ __launch_bounds__(256) void gemm_bf16_m64(const short* __restrict__ A,
                                                     const short* __restrict__ BT,
                                                     float* __restrict__ C,
                                                     int M, int N, int K) {
  __shared__ __attribute__((aligned(16))) short As[2][64 * 64];    // 8KB/buf
  __shared__ __attribute__((aligned(16))) short Bs[2][128 * 64];   // 16KB/buf
  const int tid = threadIdx.x;
  const int w = tid >> 6, l = tid & 63;
  const int g = l >> 4, lr = l & 15;
  int nbx = gridDim.x, nwg = nbx * gridDim.y;
  int flat = blockIdx.y * nbx + blockIdx.x;
  int qq = nwg >> 3;
  int f2 = (flat & 7) * qq + (flat >> 3);
  const int m0 = (f2 / nbx) * 64, n0 = (f2 % nbx) * 128;
  const int wr = w >> 1, wc = w & 1;
  f32x4 acc[2][4] = {};

  auto stage = [&](int buf, int k0) {
#pragma unroll
    for (int it = 0; it < 2; ++it) {                 // A: 512 x 16B units
      int idx = it * 256 + tid;
      int row = idx >> 3;                            // 0..63
      int scol = ((idx & 7) * 16) ^ ((row & 7) << 4);
      gload_lds16(A + (size_t)(m0 + row) * K + k0 + (scol >> 1), As[buf] + idx * 8);
    }
#pragma unroll
    for (int it = 0; it < 4; ++it) {                 // B: 1024 x 16B units
      int idx = it * 256 + tid;
      int row = idx >> 3;                            // 0..127
      int scol = ((idx & 7) * 16) ^ ((row & 7) << 4);
      gload_lds16(BT + (size_t)(n0 + row) * K + k0 + (scol >> 1), Bs[buf] + idx * 8);
    }
  };

  stage(0, 0);
  __syncthreads();
  int cur = 0;
  for (int k0 = 0; k0 < K; k0 += 64) {
    if (k0 + 64 < K) stage(cur ^ 1, k0 + 64);
#pragma unroll
    for (int ki = 0; ki < 2; ++ki) {
      const int kcol = (ki * 64 + g * 16) ^ ((lr & 7) << 4);
      short8 af[2], bfr[4];
#pragma unroll
      for (int i = 0; i < 2; ++i)
        af[i] = *(const short8*)(As[cur] + (((wr * 32 + i * 16 + lr) * 128 + kcol) >> 1));
#pragma unroll
      for (int i = 0; i < 4; ++i)
        bfr[i] = *(const short8*)(Bs[cur] + (((wc * 64 + i * 16 + lr) * 128 + kcol) >> 1));
#pragma unroll
      for (int mi = 0; mi < 2; ++mi)
#pragma unroll
        for (int ni = 0; ni < 4; ++ni)
          acc[mi][ni] = __builtin_amdgcn_mfma_f32_16x16x32_bf16(af[mi], bfr[ni], acc[mi][ni], 0, 0, 0);
    }
    __syncthreads();
    cur ^= 1;
  }
#pragma unroll
  for (int mi = 0; mi < 2; ++mi)
#pragma unroll
    for (int ni = 0; ni < 4; ++ni) {
      int row = m0 + wr * 32 + mi * 16 + g * 4;
      int col = n0 + wc * 64 + ni * 16 + lr;
#pragma unroll
      for (int r = 0; r < 4; ++r)
        C[(size_t)(row + r) * N + col] = acc[mi][ni][r];
    }
}

// gemm2: BK=64, 128x128 tile (proven R7). grid 16x16.
__global__ __launch_bounds__(256) void gemm_bf16_k64(const short* __restrict__ A,
                                                     const short* __restrict__ BT,
                                                     float* __restrict__ C,
                                                     int M, int N, int K) {
  __shared__ __attribute__((aligned(16))) short As[2][128 * 64];
  __shared__ __attribute__((aligned(16))) short Bs[2][128 * 64];
  const int tid = threadIdx.x;
  const int w = tid >> 6, l = tid & 63;
  const int g = l >> 4, lr = l & 15;
  int nbx = gridDim.x, nwg = nbx * gridDim.y;
  int flat = blockIdx.y * nbx + blockIdx.x;
  int qq = nwg >> 3;
  int f2 = (flat & 7) * qq + (flat >> 3);
  const int m0 = (f2 / nbx) * 128, n0 = (f2 % nbx) * 128;
  const int wr = w >> 1, wc = w & 1;
  f32x4 acc[4][4] = {};

  auto stage = [&](int buf, int k0) {
#pragma unroll
    for (int it = 0; it < 4; ++it) {
      int idx = it * 256 + tid;
      int row = idx >> 3;
      int colB = (idx & 7) * 16;
      int scol = colB ^ ((row & 7) << 4);
      gload_lds16(A + (size_t)(m0 + row) * K + k0 + (scol >> 1), As[buf] + idx * 8);
      gload_lds16(BT + (size_t)(n0 + row) * K + k0 + (scol >> 1), Bs[buf] + idx * 8);
    }
  };

  stage(0, 0);
  __syncthreads();
  int cur = 0;
  for (int k0 = 0; k0 < K; k0 += 64) {
    if (k0 + 64 < K) stage(cur ^ 1, k0 + 64);
#pragma unroll
    for (int ki = 0; ki < 2; ++ki) {
      short8 af[4], bfr[4];
#pragma unroll
      for (int i = 0; i < 4; ++i) {
        int off = ((wr * 64 + i * 16 + lr) * 128 + ((ki * 64 + g * 16) ^ ((lr & 7) << 4))) >> 1;
        int offb = ((wc * 64 + i * 16 + lr) * 128 + ((ki * 64 + g * 16) ^ ((lr & 7) << 4))) >> 1;
        af[i] = *(const short8*)(As[cur] + off);
        bfr[i] = *(const short8*)(Bs[cur] + offb);
      }
#pragma unroll
      for (int mi = 0; mi < 4; ++mi)
#pragma unroll
        for (int ni = 0; ni < 4; ++ni)
          acc[mi][ni] = __builtin_amdgcn_mfma_f32_16x16x32_bf16(af[mi], bfr[ni], acc[mi][ni], 0, 0, 0);
    }
    __syncthreads();
    cur ^= 1;
  }
#pragma unroll
  for (int mi = 0; mi < 4; ++mi)
#pragma unroll
    for (int ni = 0; ni < 4; ++ni) {
      int row = m0 + wr * 64 + mi * 16 + g * 4;
      int col = n0 + wc * 64 + ni * 16 + lr;
#pragma unroll
      for (int r = 0; r < 4; ++r)
        C[(size_t)(row + r) * N + col] = acc[mi][ni][r];
    }
}

// Fused prep: bid<4096 -> cvt_x; else the 4 weight transposes (flattened 160x64).
__global__ __launch_bounds__(256) void prep(const float* __restrict__ x,
                                            short* __restrict__ xb,
                                            const float* __restrict__ Wq,
                                            const float* __restrict__ Wk,
                                            const float* __restrict__ Wv,
                                            const float* __restrict__ Wo,
                                            short* __restrict__ WTqkv,
                                            short* __restrict__ WToT) {
  __shared__ float tile[32][33];
  int bid = blockIdx.x;
  int tid = threadIdx.x;
  if (bid < 4096) {
    int i = bid * 256 + tid;
    float4 v = ((const float4*)x)[i];
    short4v o;
    o.x = f2bf(v.x); o.y = f2bf(v.y); o.z = f2bf(v.z); o.w = f2bf(v.w);
    ((short4v*)xb)[i] = o;
    return;
  }
  int b = bid - 4096;
  int bx = b % 160, by = b / 160;
  const float* W;
  short* WT;
  int N, cb;
  if (bx < 64) { W = Wq; WT = WTqkv; N = 2048; cb = bx; }
  else if (bx < 80) { W = Wk; WT = WTqkv + (size_t)2048 * 2048; N = 512; cb = bx - 64; }
  else if (bx < 96) { W = Wv; WT = WTqkv + (size_t)2560 * 2048; N = 512; cb = bx - 80; }
  else { W = Wo; WT = WToT; N = 2048; cb = bx - 96; }
  int tx = tid & 31, ty = tid >> 5;
  int c0 = cb * 32, r0 = by * 32;
#pragma unroll
  for (int i = 0; i < 4; ++i)
    tile[ty + i * 8][tx] = W[(size_t)(r0 + ty + i * 8) * N + c0 + tx];
  __syncthreads();
#pragma unroll
  for (int i = 0; i < 4; ++i)
    WT[(size_t)(c0 + ty + i * 8) * 2048 + r0 + tx] = f2bf(tile[tx][ty + i * 8]);
}

// Fused qk_post + v_gate: one wave per (t, u), u in [0,24).
__global__ __launch_bounds__(256) void qkv_post(const float* __restrict__ qkv,
                                                const float* __restrict__ cosb,
                                                const float* __restrict__ sinb,
                                                const float* __restrict__ x,
                                                const float* __restrict__ ve,
                                                const float* __restrict__ Wg,
                                                float* __restrict__ outPK,
                                                float* __restrict__ outPV,
                                                short* __restrict__ qb,
                                                short* __restrict__ kb) {
  int gw = (blockIdx.x * 256 + threadIdx.x) >> 6;
  int l = threadIdx.x & 63;
  int t = gw / 24, u = gw - t * 24;
  if (t >= 2048) return;
  if (u < 20) {
    float c = cosb[t * 64 + l], s = sinb[t * 64 + l];
    const float* src = qkv + (size_t)t * 3072 + (u < 16 ? u * 128 : 2048 + (u - 16) * 128);
    float x1 = src[l], x2 = src[64 + l];
    float lo = x1 * c + x2 * s;
    float hi = x2 * c - x1 * s;
    float ss = lo * lo + hi * hi;
#pragma unroll
    for (int d = 1; d < 64; d <<= 1) ss += __shfl_xor(ss, d, 64);
    float r = rsqrtf(ss * (1.0f / 128.0f) + 1e-6f) * 1.2f;
    if (u < 16) {
      const float SCQ = 0.08838834764831845f * 1.4426950408889634f;
      float rq = r * SCQ;
      size_t b = ((size_t)u * 2048 + t) * 128;
      qb[b + l] = f2bf(lo * rq);
      qb[b + 64 + l] = f2bf(hi * rq);
    } else {
      lo *= r; hi *= r;
      int kvh = u - 16;
      size_t b = ((size_t)(2048 + t) * 4 + kvh) * 128;
      outPK[b + l] = lo;
      outPK[b + 64 + l] = hi;
      size_t b2 = ((size_t)kvh * 4096 + 2048 + t) * 128;
      kb[b2 + l] = f2bf(lo);
      kb[b2 + 64 + l] = f2bf(hi);
    }
  } else {
    int kv = u - 20;
    float z = 0.f;
#pragma unroll
    for (int j = 0; j < 12; ++j) z += x[(size_t)t * 2048 + j] * Wg[j * 4 + kv];
    float gate = 3.0f / (1.0f + expf(-z));
    const float* vr = qkv + (size_t)t * 3072 + 2560 + kv * 128;
    const float* vei = ve + (size_t)t * 512 + kv * 128;
    float v0 = vr[l] + gate * vei[l];
    float v1 = vr[64 + l] + gate * vei[64 + l];
    size_t b = ((size_t)(2048 + t) * 4 + kv) * 128;
    outPV[b + l] = v0;
    outPV[b + 64 + l] = v1;
  }
}

__global__ __launch_bounds__(256) void past_copy(const float* __restrict__ pk,
                                                 const float* __restrict__ pv,
                                                 float* __restrict__ outPK,
                                                 float* __restrict__ outPV,
                                                 short* __restrict__ kb) {
  int i = blockIdx.x * 256 + threadIdx.x;  // 0..1048575
  int d = i & 127, kv = (i >> 7) & 3, s = i >> 9;
  float a = pk[i], b = pv[i];
  outPK[i] = a;
  outPV[i] = b;
  kb[((size_t)kv * 4096 + s) * 128 + d] = f2bf(a);
}

// vbT transpose: LDS-tiled, coalesced both sides. grid (16, 128), block 256 flat.
__global__ __launch_bounds__(256) void v_transpose(const float* __restrict__ PV,
                                                   short* __restrict__ vbT) {
  __shared__ float tile[32][33];
  int tx = threadIdx.x & 31, ty = threadIdx.x >> 5;
  int c0 = blockIdx.x * 32, r0 = blockIdx.y * 32;
#pragma unroll
  for (int i = 0; i < 4; ++i)
    tile[ty + i * 8][tx] = PV[(size_t)(r0 + ty + i * 8) * 512 + c0 + tx];
  __syncthreads();
#pragma unroll
  for (int i = 0; i < 4; ++i)
    vbT[(size_t)(c0 + ty + i * 8) * 4096 + r0 + tx] = f2bf(tile[tx][ty + i * 8]);
}

// flash attention, 2-way key-split (frozen R8 structure, ~86 us).
__global__ __launch_bounds__(256, 2) void attn(const short* __restrict__ qb,
                                               const short* __restrict__ kb,
                                               const short* __restrict__ vbT,
                                               short* __restrict__ Po,
                                               float* __restrict__ ml) {
  extern __shared__ __attribute__((aligned(16))) short smem[];
  short* Ks = smem;           // [2][64][128] shorts, swizzled
  short* Vs = smem + 16384;   // [2][128][64] shorts, swizzled
  const int tid = threadIdx.x, w = tid >> 6, l = tid & 63;
  const int g = l >> 4, lr = l & 15;
  const int lid = blockIdx.x;
  const int qbi = 15 - (lid >> 5);
  const int sub = lid & 31;
  const int h = sub >> 1, cls = sub & 1;
  const int kv = h >> 2;
  const int qw = qbi * 128 + w * 32;
  char* Pw = (char*)(smem + 32768) + w * 2048;
  const short* gK = kb + (size_t)kv * 4096 * 128;
  const short* gV = vbT + (size_t)kv * 128 * 4096;
  const int nT = 34 + 2 * qbi;
  const int cnt = (nT - cls + 1) >> 1;

  short8 aq[2][4];
#pragma unroll
  for (int u = 0; u < 2; ++u)
#pragma unroll
    for (int c4 = 0; c4 < 4; ++c4)
      aq[u][c4] = *(const short8*)(qb + ((size_t)(h * 2048 + qw + u * 16 + lr)) * 128 + c4 * 32 + g * 8);

  float m_r[2] = {-INFINITY, -INFINITY};
  float l_r[2] = {0.f, 0.f};
  f32x4 o[2][8] = {};

  const int rK = tid >> 4, cKs = ((tid & 15) * 16) ^ ((rK & 7) << 4);
  const int rV = tid >> 3, cVs = ((tid & 7) * 16) ^ ((rV & 7) << 4);
  const short* kptr = gK + (size_t)(cls * 64 + rK) * 128 + (cKs >> 1);
  const short* vptr = gV + (size_t)rV * 4096 + cls * 64 + (cVs >> 1);
  short* kdst = Ks + w * 512;
  short* vdst = Vs + w * 512;

  auto stageK = [&](int buf) {
#pragma unroll
    for (int it = 0; it < 4; ++it)
      gload_lds16(kptr + it * 2048, kdst + buf * 8192 + it * 2048);
    kptr += 16384;
  };
  auto stageV = [&](int buf) {
#pragma unroll
    for (int it = 0; it < 4; ++it)
      gload_lds16(vptr + (size_t)it * 131072, vdst + buf * 8192 + it * 2048);
    vptr += 128;
  };

  stageK(0);
  stageV(0);
  __syncthreads();
  int cur = 0;
  for (int i = 0; i < cnt; ++i) {
    const int s0 = (cls + 2 * i) * 64;
    if (i + 1 < cnt) {
      stageK(cur ^ 1);
      stageV(cur ^ 1);
    }
    f32x4 sc[2][4] = {};
    __builtin_amdgcn_s_setprio(1);
#pragma unroll
    for (int cc = 0; cc < 4; ++cc) {
      const int rb = cur * 8192 + (cc * 16 + lr) * 128;
      short8 bk[4];
#pragma unroll
      for (int c4 = 0; c4 < 4; ++c4)
        bk[c4] = *(const short8*)(Ks + rb + (((c4 * 64 + g * 16) ^ ((lr & 7) << 4)) >> 1));
#pragma unroll
      for (int c4 = 0; c4 < 4; ++c4) {
        sc[0][cc] = __builtin_amdgcn_mfma_f32_16x16x32_bf16(bk[c4], aq[0][c4], sc[0][cc], 0, 0, 0);
        sc[1][cc] = __builtin_amdgcn_mfma_f32_16x16x32_bf16(bk[c4], aq[1][c4], sc[1][cc], 0, 0, 0);
      }
    }
    __builtin_amdgcn_s_setprio(0);
    if (s0 + 63 > 2048 + qw) {
#pragma unroll
      for (int u = 0; u < 2; ++u)
#pragma unroll
        for (int cc = 0; cc < 4; ++cc)
#pragma unroll
          for (int r = 0; r < 4; ++r)
            sc[u][cc][r] = (s0 + cc * 16 + g * 4 + r <= 2048 + qw + u * 16 + lr)
                               ? sc[u][cc][r] : -INFINITY;
    }
    short8 ap[2][2];
#pragma unroll
    for (int u = 0; u < 2; ++u) {
      float pmax = -INFINITY;
#pragma unroll
      for (int cc = 0; cc < 4; ++cc) {
        float a = fmaxf(fmaxf(sc[u][cc][0], sc[u][cc][1]), fmaxf(sc[u][cc][2], sc[u][cc][3]));
        pmax = fmaxf(pmax, a);
      }
      if (!__all(pmax - m_r[u] <= 8.0f)) {
        float tm = fmaxf(pmax, __shfl_xor(pmax, 16, 64));
        tm = fmaxf(tm, __shfl_xor(tm, 32, 64));
        float mn = fmaxf(m_r[u], tm);
        float corr = exp2f(m_r[u] - mn);
        m_r[u] = mn;
        l_r[u] *= corr;
        float co[4];
#pragma unroll
        for (int r = 0; r < 4; ++r) co[r] = __shfl(corr, (l & 48) | (g * 4 + r), 64);
#pragma unroll
        for (int d8 = 0; d8 < 8; ++d8) {
          f32x4 tt = o[u][d8];
#pragma unroll
          for (int r = 0; r < 4; ++r) tt[r] *= co[r];
          o[u][d8] = tt;
        }
      }
      float ps = 0.f;
#pragma unroll
      for (int cc = 0; cc < 4; ++cc) {
        float p0 = exp2f(sc[u][cc][0] - m_r[u]);
        float p1 = exp2f(sc[u][cc][1] - m_r[u]);
        float p2 = exp2f(sc[u][cc][2] - m_r[u]);
        float p3 = exp2f(sc[u][cc][3] - m_r[u]);
        ps += (p0 + p1) + (p2 + p3);
        unsigned pk0 = cvt_pk_bf16(p0, p1);
        unsigned pk1 = cvt_pk_bf16(p2, p3);
        int off8 = (lr * 128 + cc * 32 + g * 8) ^ ((lr & 7) << 4);
        unsigned long long pq = (unsigned long long)pk0 | ((unsigned long long)pk1 << 32);
        *(unsigned long long*)(Pw + off8) = pq;
      }
      l_r[u] += ps;
#pragma unroll
      for (int ks = 0; ks < 2; ++ks)
        ap[u][ks] = *(const short8*)(Pw + ((lr * 128 + ks * 64 + g * 16) ^ ((lr & 7) << 4)));
    }
    __builtin_amdgcn_s_setprio(1);
#pragma unroll
    for (int d8 = 0; d8 < 8; ++d8) {
      const int rb = cur * 8192 + (d8 * 16 + lr) * 64;
      short8 bv0 = *(const short8*)(Vs + rb + (((0 * 64 + g * 16) ^ ((lr & 7) << 4)) >> 1));
      short8 bv1 = *(const short8*)(Vs + rb + (((1 * 64 + g * 16) ^ ((lr & 7) << 4)) >> 1));
      o[0][d8] = __builtin_amdgcn_mfma_f32_16x16x32_bf16(ap[0][0], bv0, o[0][d8], 0, 0, 0);
      o[0][d8] = __builtin_amdgcn_mfma_f32_16x16x32_bf16(ap[0][1], bv1, o[0][d8], 0, 0, 0);
      o[1][d8] = __builtin_amdgcn_mfma_f32_16x16x32_bf16(ap[1][0], bv0, o[1][d8], 0, 0, 0);
      o[1][d8] = __builtin_amdgcn_mfma_f32_16x16x32_bf16(ap[1][1], bv1, o[1][d8], 0, 0, 0);
    }
    __builtin_amdgcn_s_setprio(0);
    __syncthreads();
    cur ^= 1;
  }
#pragma unroll
  for (int u = 0; u < 2; ++u) {
    float ls = l_r[u];
    ls += __shfl_xor(ls, 16, 64);
    ls += __shfl_xor(ls, 32, 64);
    float inv = 1.0f / ls;
    float invo[4];
#pragma unroll
    for (int r = 0; r < 4; ++r) invo[r] = __shfl(inv, (l & 48) | (g * 4 + r), 64);
#pragma unroll
    for (int d8 = 0; d8 < 8; ++d8)
#pragma unroll
      for (int r = 0; r < 4; ++r)
        Po[((size_t)(cls * 16 + h) * 2048 + qw + u * 16 + g * 4 + r) * 128 + d8 * 16 + lr] =
            f2h(o[u][d8][r] * invo[r]);
    if (g == 0) {
      float2 v;
      v.x = m_r[u];
      v.y = ls;
      ((float2*)ml)[(size_t)(cls * 16 + h) * 2048 + qw + u * 16 + lr] = v;
    }
  }
}

// merge 2 key-split partials -> ya (bf16). one thread per (q, h, 8-d chunk).
__global__ __launch_bounds__(256) void attn_merge(const short* __restrict__ Po,
                                                  const float* __restrict__ ml,
                                                  short* __restrict__ ya) {
  int i = blockIdx.x * 256 + threadIdx.x;  // 0..524287
  int q = i >> 8, rem = i & 255, h = rem >> 4, oct = rem & 15;
  float mc[2], lc[2];
#pragma unroll
  for (int c = 0; c < 2; ++c) {
    float2 v = ((const float2*)ml)[(size_t)(c * 16 + h) * 2048 + q];
    mc[c] = v.x; lc[c] = v.y;
  }
  float m = fmaxf(mc[0], mc[1]);
  float wsum = 0.f, acc[8] = {};
#pragma unroll
  for (int c = 0; c < 2; ++c) {
    float wc = lc[c] * exp2f(mc[c] - m);
    wsum += wc;
    short8 p = *(const short8*)(Po + ((size_t)(c * 16 + h) * 2048 + q) * 128 + oct * 8);
#pragma unroll
    for (int j = 0; j < 8; ++j) acc[j] += wc * h2f(p[j]);
  }
  float inv = 1.0f / wsum;
  short8 ov;
#pragma unroll
  for (int j = 0; j < 8; ++j) ov[j] = f2bf(acc[j] * inv);
  *(short8*)(ya + (size_t)q * 2048 + h * 128 + oct * 8) = ov;
}

extern "C" void kernel_launch(void* const* d_in, const int* in_sizes, int n_in,
                              void* d_out, int out_size, void* d_ws, size_t ws_size,
                              hipStream_t stream) {
  const float* x = (const float*)d_in[0];
  const float* ve = (const float*)d_in[1];
  const float* cosb = (const float*)d_in[2];
  const float* sinb = (const float*)d_in[3];
  const float* past_key = (const float*)d_in[4];
  const float* past_value = (const float*)d_in[5];
  const float* Wq = (const float*)d_in[6];
  const float* Wk = (const float*)d_in[7];
  const float* Wv = (const float*)d_in[8];
  const float* Wo = (const float*)d_in[9];
  const float* Wg = (const float*)d_in[10];

  float* outY = (float*)d_out;          // 2048*2048
  float* outPK = outY + 4194304;        // 4096*4*128
  float* outPV = outPK + 2097152;       // 4096*4*128

  short* base = (short*)d_ws;
  short* WToT = base;                               // 2048*2048 bf16 (live to the end)
  short* WTqkv = base + 4194304;                    // 3072*2048 bf16  (dead after gemm1)
  short* xb = WTqkv + (size_t)6291456;              // 2048*2048 bf16  (dead after gemm1)
  float* qkv = (float*)(xb + (size_t)4194304);      // 2048*3072 f32   (dead after qkv_post)
  short* qb = (short*)(qkv + (size_t)6291456);      // 16*2048*128 bf16
  short* kb = qb + (size_t)4194304;                 // 4*4096*128 bf16
  short* vbT = kb + (size_t)2097152;                // 4*128*4096 bf16 (transposed)
  short* ya = vbT + (size_t)2097152;                // 2048*2048 bf16
  // attn partials alias the dead WTqkv/xb/qkv pool:
  short* Po = WTqkv;                                // 2*16*2048*128 f16 = 8388608 shorts
  float* mlb = (float*)(base + 20971520);           // 2*16*2048 float2 = 524288 floats

  static bool attr_set = false;
  if (!attr_set) {
    (void)hipFuncSetAttribute((const void*)attn,
                              hipFuncAttributeMaxDynamicSharedMemorySize, 73728);
    attr_set = true;
  }

  prep<<<14336, 256, 0, stream>>>(x, xb, Wq, Wk, Wv, Wo, WTqkv, WToT);

  gemm_bf16_m64<<<dim3(24, 32), 256, 0, stream>>>(xb, WTqkv, qkv, 2048, 3072, 2048);

  qkv_post<<<12288, 256, 0, stream>>>(qkv, cosb, sinb, x, ve, Wg, outPK, outPV, qb, kb);
  past_copy<<<4096, 256, 0, stream>>>(past_key, past_value, outPK, outPV, kb);
  v_transpose<<<dim3(16, 128), 256, 0, stream>>>(outPV, vbT);

  attn<<<512, 256, 73728, stream>>>(qb, kb, vbT, Po, mlb);
  attn_merge<<<2048, 256, 0, stream>>>(Po, mlb, ya);

  gemm_bf16_k64<<<dim3(16, 16), 256, 0, stream>>>(ya, WToT, outY, 2048, 2048, 2048);
}

// Round 10
// 181.045 us; speedup vs baseline: 1.9086x; 1.0020x over previous
//
#include <hip/hip_runtime.h>
#include <hip/hip_bf16.h>
#include <math.h>

typedef __attribute__((ext_vector_type(8))) short short8;
typedef __attribute__((ext_vector_type(4))) short short4v;
typedef __attribute__((ext_vector_type(4))) float f32x4;

#define DEV __device__ __forceinline__

DEV short f2bf(float f) {
  unsigned u = __builtin_bit_cast(unsigned, f);
  unsigned r = (u + 0x7FFFu + ((u >> 16) & 1u)) >> 16;
  return (short)r;
}

DEV float bf2f(short s) {
  unsigned u = ((unsigned)(unsigned short)s) << 16;
  return __builtin_bit_cast(float, u);
}

DEV short f2h(float f) {
  _Float16 h = (_Float16)f;
  return __builtin_bit_cast(short, h);
}

DEV float h2f(short s) {
  return (float)__builtin_bit_cast(_Float16, s);
}

DEV unsigned cvt_pk_bf16(float lo, float hi) {
  unsigned r;
  asm("v_cvt_pk_bf16_f32 %0, %1, %2" : "=v"(r) : "v"(lo), "v"(hi));
  return r;
}

DEV void gload_lds16(const void* g, void* l) {
  __builtin_amdgcn_global_load_lds((const __attribute__((address_space(1))) void*)g,
                                   (__attribute__((address_space(3))) void*)l, 16, 0, 0);
}

// m64 GEMM core: C = A[M x K] bf16 * BT[N x K]^T. BM=64, BN=128, BK=64,
// XOR-swizzle, 2-phase dbuf, XCD swizzle. f32 output variant.
__global__ __launch_bounds__(256) void gemm_m64_f32(const short* __restrict__ A,
                                                    const short* __restrict__ BT,
                                                    float* __restrict__ C,
                                                    int M, int N, int K) {
  __shared__ __attribute__((aligned(16))) short As[2][64 * 64];
  __shared__ __attribute__((aligned(16))) short Bs[2][128 * 64];
  const int tid = threadIdx.x;
  const int w = tid >> 6, l = tid & 63;
  const int g = l >> 4, lr = l & 15;
  int nbx = gridDim.x, nwg = nbx * gridDim.y;
  int flat = blockIdx.y * nbx + blockIdx.x;
  int qq = nwg >> 3;
  int f2 = (flat & 7) * qq + (flat >> 3);
  const int m0 = (f2 / nbx) * 64, n0 = (f2 % nbx) * 128;
  const int wr = w >> 1, wc = w & 1;
  f32x4 acc[2][4] = {};

  auto stage = [&](int buf, int k0) {
#pragma unroll
    for (int it = 0; it < 2; ++it) {
      int idx = it * 256 + tid;
      int row = idx >> 3;
      int scol = ((idx & 7) * 16) ^ ((row & 7) << 4);
      gload_lds16(A + (size_t)(m0 + row) * K + k0 + (scol >> 1), As[buf] + idx * 8);
    }
#pragma unroll
    for (int it = 0; it < 4; ++it) {
      int idx = it * 256 + tid;
      int row = idx >> 3;
      int scol = ((idx & 7) * 16) ^ ((row & 7) << 4);
      gload_lds16(BT + (size_t)(n0 + row) * K + k0 + (scol >> 1), Bs[buf] + idx * 8);
    }
  };

  stage(0, 0);
  __syncthreads();
  int cur = 0;
  for (int k0 = 0; k0 < K; k0 += 64) {
    if (k0 + 64 < K) stage(cur ^ 1, k0 + 64);
#pragma unroll
    for (int ki = 0; ki < 2; ++ki) {
      const int kcol = (ki * 64 + g * 16) ^ ((lr & 7) << 4);
      short8 af[2], bfr[4];
#pragma unroll
      for (int i = 0; i < 2; ++i)
        af[i] = *(const short8*)(As[cur] + (((wr * 32 + i * 16 + lr) * 128 + kcol) >> 1));
#pragma unroll
      for (int i = 0; i < 4; ++i)
        bfr[i] = *(const short8*)(Bs[cur] + (((wc * 64 + i * 16 + lr) * 128 + kcol) >> 1));
#pragma unroll
      for (int mi = 0; mi < 2; ++mi)
#pragma unroll
        for (int ni = 0; ni < 4; ++ni)
          acc[mi][ni] = __builtin_amdgcn_mfma_f32_16x16x32_bf16(af[mi], bfr[ni], acc[mi][ni], 0, 0, 0);
    }
    __syncthreads();
    cur ^= 1;
  }
#pragma unroll
  for (int mi = 0; mi < 2; ++mi)
#pragma unroll
    for (int ni = 0; ni < 4; ++ni) {
      int row = m0 + wr * 32 + mi * 16 + g * 4;
      int col = n0 + wc * 64 + ni * 16 + lr;
#pragma unroll
      for (int r = 0; r < 4; ++r)
        C[(size_t)(row + r) * N + col] = acc[mi][ni][r];
    }
}

// bf16-output variant (for gemm1 -> qkv in bf16).
__global__ __launch_bounds__(256) void gemm_m64_bf16(const short* __restrict__ A,
                                                     const short* __restrict__ BT,
                                                     short* __restrict__ C,
                                                     int M, int N, int K) {
  __shared__ __attribute__((aligned(16))) short As[2][64 * 64];
  __shared__ __attribute__((aligned(16))) short Bs[2][128 * 64];
  const int tid = threadIdx.x;
  const int w = tid >> 6, l = tid & 63;
  const int g = l >> 4, lr = l & 15;
  int nbx = gridDim.x, nwg = nbx * gridDim.y;
  int flat = blockIdx.y * nbx + blockIdx.x;
  int qq = nwg >> 3;
  int f2 = (flat & 7) * qq + (flat >> 3);
  const int m0 = (f2 / nbx) * 64, n0 = (f2 % nbx) * 128;
  const int wr = w >> 1, wc = w & 1;
  f32x4 acc[2][4] = {};

  auto stage = [&](int buf, int k0) {
#pragma unroll
    for (int it = 0; it < 2; ++it) {
      int idx = it * 256 + tid;
      int row = idx >> 3;
      int scol = ((idx & 7) * 16) ^ ((row & 7) << 4);
      gload_lds16(A + (size_t)(m0 + row) * K + k0 + (scol >> 1), As[buf] + idx * 8);
    }
#pragma unroll
    for (int it = 0; it < 4; ++it) {
      int idx = it * 256 + tid;
      int row = idx >> 3;
      int scol = ((idx & 7) * 16) ^ ((row & 7) << 4);
      gload_lds16(BT + (size_t)(n0 + row) * K + k0 + (scol >> 1), Bs[buf] + idx * 8);
    }
  };

  stage(0, 0);
  __syncthreads();
  int cur = 0;
  for (int k0 = 0; k0 < K; k0 += 64) {
    if (k0 + 64 < K) stage(cur ^ 1, k0 + 64);
#pragma unroll
    for (int ki = 0; ki < 2; ++ki) {
      const int kcol = (ki * 64 + g * 16) ^ ((lr & 7) << 4);
      short8 af[2], bfr[4];
#pragma unroll
      for (int i = 0; i < 2; ++i)
        af[i] = *(const short8*)(As[cur] + (((wr * 32 + i * 16 + lr) * 128 + kcol) >> 1));
#pragma unroll
      for (int i = 0; i < 4; ++i)
        bfr[i] = *(const short8*)(Bs[cur] + (((wc * 64 + i * 16 + lr) * 128 + kcol) >> 1));
#pragma unroll
      for (int mi = 0; mi < 2; ++mi)
#pragma unroll
        for (int ni = 0; ni < 4; ++ni)
          acc[mi][ni] = __builtin_amdgcn_mfma_f32_16x16x32_bf16(af[mi], bfr[ni], acc[mi][ni], 0, 0, 0);
    }
    __syncthreads();
    cur ^= 1;
  }
#pragma unroll
  for (int mi = 0; mi < 2; ++mi)
#pragma unroll
    for (int ni = 0; ni < 4; ++ni) {
      int row = m0 + wr * 32 + mi * 16 + g * 4;
      int col = n0 + wc * 64 + ni * 16 + lr;
#pragma unroll
      for (int r = 0; r < 4; ++r)
        C[(size_t)(row + r) * N + col] = f2bf(acc[mi][ni][r]);
    }
}

// Fused prep: bid<4096 -> cvt_x; else the 4 weight transposes (flattened 160x64).
__global__ __launch_bounds__(256) void prep(const float* __restrict__ x,
                                            short* __restrict__ xb,
                                            const float* __restrict__ Wq,
                                            const float* __restrict__ Wk,
                                            const float* __restrict__ Wv,
                                            const float* __restrict__ Wo,
                                            short* __restrict__ WTqkv,
                                            short* __restrict__ WToT) {
  __shared__ float tile[32][33];
  int bid = blockIdx.x;
  int tid = threadIdx.x;
  if (bid < 4096) {
    int i = bid * 256 + tid;
    float4 v = ((const float4*)x)[i];
    short4v o;
    o.x = f2bf(v.x); o.y = f2bf(v.y); o.z = f2bf(v.z); o.w = f2bf(v.w);
    ((short4v*)xb)[i] = o;
    return;
  }
  int b = bid - 4096;
  int bx = b % 160, by = b / 160;
  const float* W;
  short* WT;
  int N, cb;
  if (bx < 64) { W = Wq; WT = WTqkv; N = 2048; cb = bx; }
  else if (bx < 80) { W = Wk; WT = WTqkv + (size_t)2048 * 2048; N = 512; cb = bx - 64; }
  else if (bx < 96) { W = Wv; WT = WTqkv + (size_t)2560 * 2048; N = 512; cb = bx - 80; }
  else { W = Wo; WT = WToT; N = 2048; cb = bx - 96; }
  int tx = tid & 31, ty = tid >> 5;
  int c0 = cb * 32, r0 = by * 32;
#pragma unroll
  for (int i = 0; i < 4; ++i)
    tile[ty + i * 8][tx] = W[(size_t)(r0 + ty + i * 8) * N + c0 + tx];
  __syncthreads();
#pragma unroll
  for (int i = 0; i < 4; ++i)
    WT[(size_t)(c0 + ty + i * 8) * 2048 + r0 + tx] = f2bf(tile[tx][ty + i * 8]);
}

// Fused qk_post + v_gate: one wave per (t, u), u in [0,24). qkv is bf16 now.
__global__ __launch_bounds__(256) void qkv_post(const short* __restrict__ qkv,
                                                const float* __restrict__ cosb,
                                                const float* __restrict__ sinb,
                                                const float* __restrict__ x,
                                                const float* __restrict__ ve,
                                                const float* __restrict__ Wg,
                                                float* __restrict__ outPK,
                                                float* __restrict__ outPV,
                                                short* __restrict__ qb,
                                                short* __restrict__ kb) {
  int gw = (blockIdx.x * 256 + threadIdx.x) >> 6;
  int l = threadIdx.x & 63;
  int t = gw / 24, u = gw - t * 24;
  if (t >= 2048) return;
  if (u < 20) {
    float c = cosb[t * 64 + l], s = sinb[t * 64 + l];
    const short* src = qkv + (size_t)t * 3072 + (u < 16 ? u * 128 : 2048 + (u - 16) * 128);
    float x1 = bf2f(src[l]), x2 = bf2f(src[64 + l]);
    float lo = x1 * c + x2 * s;
    float hi = x2 * c - x1 * s;
    float ss = lo * lo + hi * hi;
#pragma unroll
    for (int d = 1; d < 64; d <<= 1) ss += __shfl_xor(ss, d, 64);
    float r = rsqrtf(ss * (1.0f / 128.0f) + 1e-6f) * 1.2f;
    if (u < 16) {
      const float SCQ = 0.08838834764831845f * 1.4426950408889634f;
      float rq = r * SCQ;
      size_t b = ((size_t)u * 2048 + t) * 128;
      qb[b + l] = f2bf(lo * rq);
      qb[b + 64 + l] = f2bf(hi * rq);
    } else {
      lo *= r; hi *= r;
      int kvh = u - 16;
      size_t b = ((size_t)(2048 + t) * 4 + kvh) * 128;
      outPK[b + l] = lo;
      outPK[b + 64 + l] = hi;
      size_t b2 = ((size_t)kvh * 4096 + 2048 + t) * 128;
      kb[b2 + l] = f2bf(lo);
      kb[b2 + 64 + l] = f2bf(hi);
    }
  } else {
    int kv = u - 20;
    float z = 0.f;
#pragma unroll
    for (int j = 0; j < 12; ++j) z += x[(size_t)t * 2048 + j] * Wg[j * 4 + kv];
    float gate = 3.0f / (1.0f + expf(-z));
    const short* vr = qkv + (size_t)t * 3072 + 2560 + kv * 128;
    const float* vei = ve + (size_t)t * 512 + kv * 128;
    float v0 = bf2f(vr[l]) + gate * vei[l];
    float v1 = bf2f(vr[64 + l]) + gate * vei[64 + l];
    size_t b = ((size_t)(2048 + t) * 4 + kv) * 128;
    outPV[b + l] = v0;
    outPV[b + 64 + l] = v1;
  }
}

// past copy, K only (PV handled by v_transpose).
__global__ __launch_bounds__(256) void past_copy(const float* __restrict__ pk,
                                                 float* __restrict__ outPK,
                                                 short* __restrict__ kb) {
  int i = blockIdx.x * 256 + threadIdx.x;  // 0..1048575
  int d = i & 127, kv = (i >> 7) & 3, s = i >> 9;
  float a = pk[i];
  outPK[i] = a;
  kb[((size_t)kv * 4096 + s) * 128 + d] = f2bf(a);
}

// vbT transpose + past-PV copy fused: rows < 2048 read pv (and write outPV);
// rows >= 2048 read outPV (written by qkv_post). grid (16, 128), block 256.
__global__ __launch_bounds__(256) void v_transpose(const float* __restrict__ pv,
                                                   float* __restrict__ outPV,
                                                   short* __restrict__ vbT) {
  __shared__ float tile[32][33];
  int tx = threadIdx.x & 31, ty = threadIdx.x >> 5;
  int c0 = blockIdx.x * 32, r0 = blockIdx.y * 32;
  if (r0 < 2048) {
#pragma unroll
    for (int i = 0; i < 4; ++i) {
      float v = pv[(size_t)(r0 + ty + i * 8) * 512 + c0 + tx];
      tile[ty + i * 8][tx] = v;
      outPV[(size_t)(r0 + ty + i * 8) * 512 + c0 + tx] = v;
    }
  } else {
#pragma unroll
    for (int i = 0; i < 4; ++i)
      tile[ty + i * 8][tx] = outPV[(size_t)(r0 + ty + i * 8) * 512 + c0 + tx];
  }
  __syncthreads();
#pragma unroll
  for (int i = 0; i < 4; ++i)
    vbT[(size_t)(c0 + ty + i * 8) * 4096 + r0 + tx] = f2bf(tile[tx][ty + i * 8]);
}

// flash attention, 2-way key-split (frozen R8 structure, ~86 us).
__global__ __launch_bounds__(256, 2) void attn(const short* __restrict__ qb,
                                               const short* __restrict__ kb,
                                               const short* __restrict__ vbT,
                                               short* __restrict__ Po,
                                               float* __restrict__ ml) {
  extern __shared__ __attribute__((aligned(16))) short smem[];
  short* Ks = smem;           // [2][64][128] shorts, swizzled
  short* Vs = smem + 16384;   // [2][128][64] shorts, swizzled
  const int tid = threadIdx.x, w = tid >> 6, l = tid & 63;
  const int g = l >> 4, lr = l & 15;
  const int lid = blockIdx.x;
  const int qbi = 15 - (lid >> 5);
  const int sub = lid & 31;
  const int h = sub >> 1, cls = sub & 1;
  const int kv = h >> 2;
  const int qw = qbi * 128 + w * 32;
  char* Pw = (char*)(smem + 32768) + w * 2048;
  const short* gK = kb + (size_t)kv * 4096 * 128;
  const short* gV = vbT + (size_t)kv * 128 * 4096;
  const int nT = 34 + 2 * qbi;
  const int cnt = (nT - cls + 1) >> 1;

  short8 aq[2][4];
#pragma unroll
  for (int u = 0; u < 2; ++u)
#pragma unroll
    for (int c4 = 0; c4 < 4; ++c4)
      aq[u][c4] = *(const short8*)(qb + ((size_t)(h * 2048 + qw + u * 16 + lr)) * 128 + c4 * 32 + g * 8);

  float m_r[2] = {-INFINITY, -INFINITY};
  float l_r[2] = {0.f, 0.f};
  f32x4 o[2][8] = {};

  const int rK = tid >> 4, cKs = ((tid & 15) * 16) ^ ((rK & 7) << 4);
  const int rV = tid >> 3, cVs = ((tid & 7) * 16) ^ ((rV & 7) << 4);
  const short* kptr = gK + (size_t)(cls * 64 + rK) * 128 + (cKs >> 1);
  const short* vptr = gV + (size_t)rV * 4096 + cls * 64 + (cVs >> 1);
  short* kdst = Ks + w * 512;
  short* vdst = Vs + w * 512;

  auto stageK = [&](int buf) {
#pragma unroll
    for (int it = 0; it < 4; ++it)
      gload_lds16(kptr + it * 2048, kdst + buf * 8192 + it * 2048);
    kptr += 16384;
  };
  auto stageV = [&](int buf) {
#pragma unroll
    for (int it = 0; it < 4; ++it)
      gload_lds16(vptr + (size_t)it * 131072, vdst + buf * 8192 + it * 2048);
    vptr += 128;
  };

  stageK(0);
  stageV(0);
  __syncthreads();
  int cur = 0;
  for (int i = 0; i < cnt; ++i) {
    const int s0 = (cls + 2 * i) * 64;
    if (i + 1 < cnt) {
      stageK(cur ^ 1);
      stageV(cur ^ 1);
    }
    f32x4 sc[2][4] = {};
    __builtin_amdgcn_s_setprio(1);
#pragma unroll
    for (int cc = 0; cc < 4; ++cc) {
      const int rb = cur * 8192 + (cc * 16 + lr) * 128;
      short8 bk[4];
#pragma unroll
      for (int c4 = 0; c4 < 4; ++c4)
        bk[c4] = *(const short8*)(Ks + rb + (((c4 * 64 + g * 16) ^ ((lr & 7) << 4)) >> 1));
#pragma unroll
      for (int c4 = 0; c4 < 4; ++c4) {
        sc[0][cc] = __builtin_amdgcn_mfma_f32_16x16x32_bf16(bk[c4], aq[0][c4], sc[0][cc], 0, 0, 0);
        sc[1][cc] = __builtin_amdgcn_mfma_f32_16x16x32_bf16(bk[c4], aq[1][c4], sc[1][cc], 0, 0, 0);
      }
    }
    __builtin_amdgcn_s_setprio(0);
    if (s0 + 63 > 2048 + qw) {
#pragma unroll
      for (int u = 0; u < 2; ++u)
#pragma unroll
        for (int cc = 0; cc < 4; ++cc)
#pragma unroll
          for (int r = 0; r < 4; ++r)
            sc[u][cc][r] = (s0 + cc * 16 + g * 4 + r <= 2048 + qw + u * 16 + lr)
                               ? sc[u][cc][r] : -INFINITY;
    }
    short8 ap[2][2];
#pragma unroll
    for (int u = 0; u < 2; ++u) {
      float pmax = -INFINITY;
#pragma unroll
      for (int cc = 0; cc < 4; ++cc) {
        float a = fmaxf(fmaxf(sc[u][cc][0], sc[u][cc][1]), fmaxf(sc[u][cc][2], sc[u][cc][3]));
        pmax = fmaxf(pmax, a);
      }
      if (!__all(pmax - m_r[u] <= 8.0f)) {
        float tm = fmaxf(pmax, __shfl_xor(pmax, 16, 64));
        tm = fmaxf(tm, __shfl_xor(tm, 32, 64));
        float mn = fmaxf(m_r[u], tm);
        float corr = exp2f(m_r[u] - mn);
        m_r[u] = mn;
        l_r[u] *= corr;
        float co[4];
#pragma unroll
        for (int r = 0; r < 4; ++r) co[r] = __shfl(corr, (l & 48) | (g * 4 + r), 64);
#pragma unroll
        for (int d8 = 0; d8 < 8; ++d8) {
          f32x4 tt = o[u][d8];
#pragma unroll
          for (int r = 0; r < 4; ++r) tt[r] *= co[r];
          o[u][d8] = tt;
        }
      }
      float ps = 0.f;
#pragma unroll
      for (int cc = 0; cc < 4; ++cc) {
        float p0 = exp2f(sc[u][cc][0] - m_r[u]);
        float p1 = exp2f(sc[u][cc][1] - m_r[u]);
        float p2 = exp2f(sc[u][cc][2] - m_r[u]);
        float p3 = exp2f(sc[u][cc][3] - m_r[u]);
        ps += (p0 + p1) + (p2 + p3);
        unsigned pk0 = cvt_pk_bf16(p0, p1);
        unsigned pk1 = cvt_pk_bf16(p2, p3);
        int off8 = (lr * 128 + cc * 32 + g * 8) ^ ((lr & 7) << 4);
        unsigned long long pq = (unsigned long long)pk0 | ((unsigned long long)pk1 << 32);
        *(unsigned long long*)(Pw + off8) = pq;
      }
      l_r[u] += ps;
#pragma unroll
      for (int ks = 0; ks < 2; ++ks)
        ap[u][ks] = *(const short8*)(Pw + ((lr * 128 + ks * 64 + g * 16) ^ ((lr & 7) << 4)));
    }
    __builtin_amdgcn_s_setprio(1);
#pragma unroll
    for (int d8 = 0; d8 < 8; ++d8) {
      const int rb = cur * 8192 + (d8 * 16 + lr) * 64;
      short8 bv0 = *(const short8*)(Vs + rb + (((0 * 64 + g * 16) ^ ((lr & 7) << 4)) >> 1));
      short8 bv1 = *(const short8*)(Vs + rb + (((1 * 64 + g * 16) ^ ((lr & 7) << 4)) >> 1));
      o[0][d8] = __builtin_amdgcn_mfma_f32_16x16x32_bf16(ap[0][0], bv0, o[0][d8], 0, 0, 0);
      o[0][d8] = __builtin_amdgcn_mfma_f32_16x16x32_bf16(ap[0][1], bv1, o[0][d8], 0, 0, 0);
      o[1][d8] = __builtin_amdgcn_mfma_f32_16x16x32_bf16(ap[1][0], bv0, o[1][d8], 0, 0, 0);
      o[1][d8] = __builtin_amdgcn_mfma_f32_16x16x32_bf16(ap[1][1], bv1, o[1][d8], 0, 0, 0);
    }
    __builtin_amdgcn_s_setprio(0);
    __syncthreads();
    cur ^= 1;
  }
#pragma unroll
  for (int u = 0; u < 2; ++u) {
    float ls = l_r[u];
    ls += __shfl_xor(ls, 16, 64);
    ls += __shfl_xor(ls, 32, 64);
    float inv = 1.0f / ls;
    float invo[4];
#pragma unroll
    for (int r = 0; r < 4; ++r) invo[r] = __shfl(inv, (l & 48) | (g * 4 + r), 64);
#pragma unroll
    for (int d8 = 0; d8 < 8; ++d8)
#pragma unroll
      for (int r = 0; r < 4; ++r)
        Po[((size_t)(cls * 16 + h) * 2048 + qw + u * 16 + g * 4 + r) * 128 + d8 * 16 + lr] =
            f2h(o[u][d8][r] * invo[r]);
    if (g == 0) {
      float2 v;
      v.x = m_r[u];
      v.y = ls;
      ((float2*)ml)[(size_t)(cls * 16 + h) * 2048 + qw + u * 16 + lr] = v;
    }
  }
}

// merge 2 key-split partials -> ya (bf16). one thread per (q, h, 8-d chunk).
__global__ __launch_bounds__(256) void attn_merge(const short* __restrict__ Po,
                                                  const float* __restrict__ ml,
                                                  short* __restrict__ ya) {
  int i = blockIdx.x * 256 + threadIdx.x;  // 0..524287
  int q = i >> 8, rem = i & 255, h = rem >> 4, oct = rem & 15;
  float mc[2], lc[2];
#pragma unroll
  for (int c = 0; c < 2; ++c) {
    float2 v = ((const float2*)ml)[(size_t)(c * 16 + h) * 2048 + q];
    mc[c] = v.x; lc[c] = v.y;
  }
  float m = fmaxf(mc[0], mc[1]);
  float wsum = 0.f, acc[8] = {};
#pragma unroll
  for (int c = 0; c < 2; ++c) {
    float wc = lc[c] * exp2f(mc[c] - m);
    wsum += wc;
    short8 p = *(const short8*)(Po + ((size_t)(c * 16 + h) * 2048 + q) * 128 + oct * 8);
#pragma unroll
    for (int j = 0; j < 8; ++j) acc[j] += wc * h2f(p[j]);
  }
  float inv = 1.0f / wsum;
  short8 ov;
#pragma unroll
  for (int j = 0; j < 8; ++j) ov[j] = f2bf(acc[j] * inv);
  *(short8*)(ya + (size_t)q * 2048 + h * 128 + oct * 8) = ov;
}

extern "C" void kernel_launch(void* const* d_in, const int* in_sizes, int n_in,
                              void* d_out, int out_size, void* d_ws, size_t ws_size,
                              hipStream_t stream) {
  const float* x = (const float*)d_in[0];
  const float* ve = (const float*)d_in[1];
  const float* cosb = (const float*)d_in[2];
  const float* sinb = (const float*)d_in[3];
  const float* past_key = (const float*)d_in[4];
  const float* past_value = (const float*)d_in[5];
  const float* Wq = (const float*)d_in[6];
  const float* Wk = (const float*)d_in[7];
  const float* Wv = (const float*)d_in[8];
  const float* Wo = (const float*)d_in[9];
  const float* Wg = (const float*)d_in[10];

  float* outY = (float*)d_out;          // 2048*2048
  float* outPK = outY + 4194304;        // 4096*4*128
  float* outPV = outPK + 2097152;       // 4096*4*128

  short* base = (short*)d_ws;
  short* WToT = base;                               // 2048*2048 bf16 (live to the end)
  short* WTqkv = base + 4194304;                    // 3072*2048 bf16  (dead after gemm1)
  short* xb = WTqkv + (size_t)6291456;              // 2048*2048 bf16  (dead after gemm1)
  short* qkv = xb + (size_t)4194304;                // 2048*3072 bf16  (dead after qkv_post)
  short* qb = qkv + (size_t)12582912;               // 16*2048*128 bf16 (same addr as before)
  short* kb = qb + (size_t)4194304;                 // 4*4096*128 bf16
  short* vbT = kb + (size_t)2097152;                // 4*128*4096 bf16 (transposed)
  short* ya = vbT + (size_t)2097152;                // 2048*2048 bf16
  // attn partials alias the dead WTqkv/xb pool:
  short* Po = WTqkv;                                // 2*16*2048*128 f16 = 8388608 shorts
  float* mlb = (float*)(base + 20971520);           // 2*16*2048 float2 = 524288 floats

  static bool attr_set = false;
  if (!attr_set) {
    (void)hipFuncSetAttribute((const void*)attn,
                              hipFuncAttributeMaxDynamicSharedMemorySize, 73728);
    attr_set = true;
  }

  prep<<<14336, 256, 0, stream>>>(x, xb, Wq, Wk, Wv, Wo, WTqkv, WToT);

  gemm_m64_bf16<<<dim3(24, 32), 256, 0, stream>>>(xb, WTqkv, qkv, 2048, 3072, 2048);

  qkv_post<<<12288, 256, 0, stream>>>(qkv, cosb, sinb, x, ve, Wg, outPK, outPV, qb, kb);
  past_copy<<<4096, 256, 0, stream>>>(past_key, outPK, kb);
  v_transpose<<<dim3(16, 128), 256, 0, stream>>>(past_value, outPV, vbT);

  attn<<<512, 256, 73728, stream>>>(qb, kb, vbT, Po, mlb);
  attn_merge<<<2048, 256, 0, stream>>>(Po, mlb, ya);

  gemm_m64_f32<<<dim3(16, 32), 256, 0, stream>>>(ya, WToT, outY, 2048, 2048, 2048);
}